// Round 1
// baseline (391.629 us; speedup 1.0000x reference)
//
#include <hip/hip_runtime.h>
#include <stdint.h>

// dims
#define BB 512
#define SS 64
#define HH 1024
#define EE 256
#define VV 128

typedef __attribute__((ext_vector_type(8))) short bf16x8;
typedef __attribute__((ext_vector_type(4))) float f32x4;

__device__ __forceinline__ unsigned short f2bf(float f) {
  unsigned int u = __float_as_uint(f);
  unsigned int r = (u + 0x7FFFu + ((u >> 16) & 1u)) >> 16;
  return (unsigned short)r;
}
__device__ __forceinline__ float bf2f(unsigned short h) {
  return __uint_as_float(((unsigned int)h) << 16);
}

__device__ __forceinline__ void gload_lds16(const void* g, void* l) {
  __builtin_amdgcn_global_load_lds(
      (const __attribute__((address_space(1))) unsigned int*)g,
      (__attribute__((address_space(3))) unsigned int*)l, 16, 0, 0);
}

// ---------------- conversion kernels ----------------
__global__ void cvt_f32_bf16(const float* __restrict__ in,
                             unsigned short* __restrict__ out, int n4) {
  int i = blockIdx.x * blockDim.x + threadIdx.x;
  if (i >= n4) return;
  float4 v = ((const float4*)in)[i];
  ushort4 o;
  o.x = f2bf(v.x); o.y = f2bf(v.y); o.z = f2bf(v.z); o.w = f2bf(v.w);
  ((ushort4*)out)[i] = o;
}

// out[c*R + r] = bf16(in[r*C + c])   (R, C multiples of 32)
__global__ void transpose_cvt(const float* __restrict__ in,
                              unsigned short* __restrict__ out, int R, int C) {
  __shared__ float tile[32][33];
  int bc = blockIdx.x * 32, br = blockIdx.y * 32;
  int tx = threadIdx.x & 31, ty = threadIdx.x >> 5;  // 32 x 8
#pragma unroll
  for (int i = 0; i < 32; i += 8)
    tile[ty + i][tx] = in[(long)(br + ty + i) * C + bc + tx];
  __syncthreads();
#pragma unroll
  for (int i = 0; i < 32; i += 8)
    out[(long)(bc + ty + i) * R + br + tx] = f2bf(tile[tx][ty + i]);
}

// ---------------- generic bf16 MFMA GEMM: C = A(MxK) * Bt(NxK)^T ----------------
template <int ACCUM, int BIAS>
__global__ __launch_bounds__(256) void gemm_bt(
    const unsigned short* __restrict__ A, const unsigned short* __restrict__ Bt,
    float* __restrict__ C, const float* __restrict__ bias, int N, int K) {
  __shared__ alignas(128) unsigned short lA[128 * 64];
  __shared__ alignas(128) unsigned short lB[128 * 64];
  const int tid = threadIdx.x;
  const int lane = tid & 63, wid = tid >> 6;
  const int wr = wid >> 1, wc = wid & 1;
  const int fr = lane & 15, fg = lane >> 4;
  f32x4 acc[4][4] = {};
  const long rowA0 = (long)blockIdx.x * 128;
  const long rowB0 = (long)blockIdx.y * 128;
  for (int kt = 0; kt < K; kt += 64) {
#pragma unroll
    for (int j = 0; j < 4; ++j) {
      int c = j * 256 + tid;
      int r = c >> 3, cc = c & 7;
      gload_lds16(A + (rowA0 + r) * K + kt + cc * 8, &lA[c * 8]);
    }
#pragma unroll
    for (int j = 0; j < 4; ++j) {
      int c = j * 256 + tid;
      int r = c >> 3, cc = c & 7;
      gload_lds16(Bt + (rowB0 + r) * K + kt + cc * 8, &lB[c * 8]);
    }
    __syncthreads();
#pragma unroll
    for (int kk = 0; kk < 64; kk += 32) {
      bf16x8 af[4], bfv[4];
#pragma unroll
      for (int m = 0; m < 4; ++m)
        af[m] = *(const bf16x8*)&lA[(wr * 64 + m * 16 + fr) * 64 + kk + fg * 8];
#pragma unroll
      for (int n = 0; n < 4; ++n)
        bfv[n] = *(const bf16x8*)&lB[(wc * 64 + n * 16 + fr) * 64 + kk + fg * 8];
#pragma unroll
      for (int m = 0; m < 4; ++m)
#pragma unroll
        for (int n = 0; n < 4; ++n)
          acc[m][n] = __builtin_amdgcn_mfma_f32_16x16x32_bf16(af[m], bfv[n],
                                                              acc[m][n], 0, 0, 0);
    }
    __syncthreads();
  }
#pragma unroll
  for (int m = 0; m < 4; ++m)
#pragma unroll
    for (int n = 0; n < 4; ++n)
#pragma unroll
      for (int r = 0; r < 4; ++r) {
        long grow = rowA0 + wr * 64 + m * 16 + fg * 4 + r;
        long gcol = rowB0 + wc * 64 + n * 16 + fr;
        float v = acc[m][n][r];
        if (ACCUM) v += C[grow * N + gcol];
        if (BIAS) v += bias[gcol];
        C[grow * N + gcol] = v;
      }
}

// ---------------- t1 GEMM fused with score: e[row] += sum_n tanh(t1+t2)*Vw ----------------
__global__ __launch_bounds__(256) void gemm_score(
    const unsigned short* __restrict__ A, const unsigned short* __restrict__ Bt,
    const float* __restrict__ t2, const float* __restrict__ Vw,
    float* __restrict__ e, int K) {
  __shared__ alignas(128) unsigned short lA[128 * 64];
  __shared__ alignas(128) unsigned short lB[128 * 64];
  const int tid = threadIdx.x;
  const int lane = tid & 63, wid = tid >> 6;
  const int wr = wid >> 1, wc = wid & 1;
  const int fr = lane & 15, fg = lane >> 4;
  f32x4 acc[4][4] = {};
  const long rowA0 = (long)blockIdx.x * 128;
  const long rowB0 = (long)blockIdx.y * 128;
  for (int kt = 0; kt < K; kt += 64) {
#pragma unroll
    for (int j = 0; j < 4; ++j) {
      int c = j * 256 + tid;
      int r = c >> 3, cc = c & 7;
      gload_lds16(A + (rowA0 + r) * K + kt + cc * 8, &lA[c * 8]);
    }
#pragma unroll
    for (int j = 0; j < 4; ++j) {
      int c = j * 256 + tid;
      int r = c >> 3, cc = c & 7;
      gload_lds16(Bt + (rowB0 + r) * K + kt + cc * 8, &lB[c * 8]);
    }
    __syncthreads();
#pragma unroll
    for (int kk = 0; kk < 64; kk += 32) {
      bf16x8 af[4], bfv[4];
#pragma unroll
      for (int m = 0; m < 4; ++m)
        af[m] = *(const bf16x8*)&lA[(wr * 64 + m * 16 + fr) * 64 + kk + fg * 8];
#pragma unroll
      for (int n = 0; n < 4; ++n)
        bfv[n] = *(const bf16x8*)&lB[(wc * 64 + n * 16 + fr) * 64 + kk + fg * 8];
#pragma unroll
      for (int m = 0; m < 4; ++m)
#pragma unroll
        for (int n = 0; n < 4; ++n)
          acc[m][n] = __builtin_amdgcn_mfma_f32_16x16x32_bf16(af[m], bfv[n],
                                                              acc[m][n], 0, 0, 0);
    }
    __syncthreads();
  }
  // epilogue: rows are (b*64+s); t2 indexed by b, col; Vw by col
#pragma unroll
  for (int m = 0; m < 4; ++m) {
    float part[4] = {0.f, 0.f, 0.f, 0.f};
#pragma unroll
    for (int n = 0; n < 4; ++n) {
      long gcol = rowB0 + wc * 64 + n * 16 + fr;
      float vw = Vw[gcol];
#pragma unroll
      for (int r = 0; r < 4; ++r) {
        long grow = rowA0 + wr * 64 + m * 16 + fg * 4 + r;
        long b = grow >> 6;
        float t = acc[m][n][r] + t2[b * HH + gcol];
        // tanh(t) = 1 - 2/(exp(2t)+1), overflow-safe
        float th = 1.f - 2.f / (__expf(2.f * t) + 1.f);
        part[r] += th * vw;
      }
    }
#pragma unroll
    for (int r = 0; r < 4; ++r) {
      float p = part[r];
      p += __shfl_xor(p, 1);
      p += __shfl_xor(p, 2);
      p += __shfl_xor(p, 4);
      p += __shfl_xor(p, 8);
      if (fr == 0) {
        long grow = rowA0 + wr * 64 + m * 16 + fg * 4 + r;
        atomicAdd(&e[grow], p);
      }
    }
  }
}

// ---------------- softmax over S=64, one wave per batch row ----------------
__global__ void softmax64(const float* __restrict__ e, float* __restrict__ a) {
  int b = blockIdx.x * 4 + (threadIdx.x >> 6);
  int s = threadIdx.x & 63;
  float v = e[b * 64 + s];
  float mx = v;
#pragma unroll
  for (int o = 32; o; o >>= 1) mx = fmaxf(mx, __shfl_xor(mx, o));
  float ex = __expf(v - mx);
  float sm = ex;
#pragma unroll
  for (int o = 32; o; o >>= 1) sm += __shfl_xor(sm, o);
  a[b * 64 + s] = ex / sm;
}

// ---------------- context: ct[b,h] = sum_s a[b,s]*enc[b,s,h] ----------------
__global__ void ctx_kernel(const float* __restrict__ a,
                           const unsigned short* __restrict__ encb,
                           float* __restrict__ ct) {
  int idx = blockIdx.x * 256 + threadIdx.x;  // 512*1024
  int b = idx >> 10, h = idx & 1023;
  const float* ar = a + b * 64;
  const unsigned short* er = encb + (long)b * (SS * HH) + h;
  float s = 0.f;
#pragma unroll 8
  for (int i = 0; i < 64; ++i) s += ar[i] * bf2f(er[(long)i * HH]);
  ct[idx] = s;
}

// ---------------- x = concat(emb[ids], ct) -> bf16 ----------------
__global__ void build_x(const int* __restrict__ ids, const float* __restrict__ emb,
                        const float* __restrict__ ct, unsigned short* __restrict__ xb) {
  int idx = blockIdx.x * 256 + threadIdx.x;  // 512*1280
  if (idx >= BB * (EE + HH)) return;
  int b = idx / (EE + HH), c = idx - b * (EE + HH);
  float v = (c < EE) ? emb[ids[b] * EE + c] : ct[b * HH + (c - EE)];
  xb[idx] = f2bf(v);
}

// ---------------- LSTM cell elementwise ----------------
__global__ void lstm_cell(const float* __restrict__ g, const float* __restrict__ bih,
                          const float* __restrict__ bhh, const float* __restrict__ cin,
                          float* __restrict__ hout, float* __restrict__ cout,
                          unsigned short* __restrict__ hb) {
  int idx = blockIdx.x * 256 + threadIdx.x;  // 512*1024
  int b = idx >> 10, h = idx & 1023;
  const float* gr = g + (long)b * 4096;
  float gi = gr[h] + bih[h] + bhh[h];
  float gf = gr[1024 + h] + bih[1024 + h] + bhh[1024 + h];
  float gg = gr[2048 + h] + bih[2048 + h] + bhh[2048 + h];
  float go = gr[3072 + h] + bih[3072 + h] + bhh[3072 + h];
  float si = 1.f / (1.f + __expf(-gi));
  float sf = 1.f / (1.f + __expf(-gf));
  float so = 1.f / (1.f + __expf(-go));
  float tg = 1.f - 2.f / (__expf(2.f * gg) + 1.f);
  float c2 = sf * cin[idx] + si * tg;
  float tc = 1.f - 2.f / (__expf(2.f * c2) + 1.f);
  float h2 = so * tc;
  cout[idx] = c2;
  hout[idx] = h2;
  hb[idx] = f2bf(h2);
}

extern "C" void kernel_launch(void* const* d_in, const int* in_sizes, int n_in,
                              void* d_out, int out_size, void* d_ws, size_t ws_size,
                              hipStream_t stream) {
  const int* ids = (const int*)d_in[0];
  const float* hidden = (const float*)d_in[1];
  const float* cell = (const float*)d_in[2];
  const float* enc = (const float*)d_in[3];
  const float* emb = (const float*)d_in[4];
  const float* U = (const float*)d_in[5];
  const float* W = (const float*)d_in[6];
  const float* Vw = (const float*)d_in[7];
  const float* Wih0 = (const float*)d_in[8];
  const float* Whh0 = (const float*)d_in[9];
  const float* bih0 = (const float*)d_in[10];
  const float* bhh0 = (const float*)d_in[11];
  const float* Wih1 = (const float*)d_in[12];
  const float* Whh1 = (const float*)d_in[13];
  const float* bih1 = (const float*)d_in[14];
  const float* bhh1 = (const float*)d_in[15];
  const float* out_w = (const float*)d_in[16];
  const float* out_b = (const float*)d_in[17];
  float* out = (float*)d_out;

  char* ws = (char*)d_ws;
  size_t off = 0;
  auto alloc = [&](size_t bytes) {
    char* p = ws + off;
    off += (bytes + 255) & ~(size_t)255;
    return p;
  };
  unsigned short* enc_b = (unsigned short*)alloc((size_t)BB * SS * HH * 2);  // 67MB
  unsigned short* Ut = (unsigned short*)alloc((size_t)HH * HH * 2);
  unsigned short* Wt = (unsigned short*)alloc((size_t)HH * HH * 2);
  unsigned short* Wih0b = (unsigned short*)alloc((size_t)4 * HH * (EE + HH) * 2);
  unsigned short* Whh0b = (unsigned short*)alloc((size_t)4 * HH * HH * 2);
  unsigned short* Wih1b = (unsigned short*)alloc((size_t)4 * HH * HH * 2);
  unsigned short* Whh1b = (unsigned short*)alloc((size_t)4 * HH * HH * 2);
  unsigned short* outwb = (unsigned short*)alloc((size_t)VV * HH * 2);
  unsigned short* hlastb = (unsigned short*)alloc((size_t)BB * HH * 2);
  unsigned short* hid0b = (unsigned short*)alloc((size_t)BB * HH * 2);
  float* t2 = (float*)alloc((size_t)BB * HH * 4);
  float* e = (float*)alloc((size_t)BB * SS * 4);
  float* a = (float*)alloc((size_t)BB * SS * 4);
  float* ctf = (float*)alloc((size_t)BB * HH * 4);
  unsigned short* xb = (unsigned short*)alloc((size_t)BB * (EE + HH) * 2);
  float* g = (float*)alloc((size_t)BB * 4 * HH * 4);
  unsigned short* h0b = (unsigned short*)alloc((size_t)BB * HH * 2);
  unsigned short* h1b = (unsigned short*)alloc((size_t)BB * HH * 2);
  (void)ws_size; (void)in_sizes; (void)n_in; (void)out_size;

  // output layout: out(512*128) | h_new(2*512*1024) | c_new(2*512*1024)
  float* out_logits = out;
  float* h_new = out + BB * VV;
  float* c_new = h_new + 2 * BB * HH;

  // ---- conversions ----
  cvt_f32_bf16<<<(BB * SS * HH / 4 + 255) / 256, 256, 0, stream>>>(enc, enc_b, BB * SS * HH / 4);
  cvt_f32_bf16<<<(BB * HH / 4 + 255) / 256, 256, 0, stream>>>(hidden + BB * HH, hlastb, BB * HH / 4);
  cvt_f32_bf16<<<(BB * HH / 4 + 255) / 256, 256, 0, stream>>>(hidden, hid0b, BB * HH / 4);
  transpose_cvt<<<dim3(HH / 32, HH / 32), 256, 0, stream>>>(U, Ut, HH, HH);
  transpose_cvt<<<dim3(HH / 32, HH / 32), 256, 0, stream>>>(W, Wt, HH, HH);
  cvt_f32_bf16<<<(4 * HH * (EE + HH) / 4 + 255) / 256, 256, 0, stream>>>(Wih0, Wih0b, 4 * HH * (EE + HH) / 4);
  cvt_f32_bf16<<<(4 * HH * HH / 4 + 255) / 256, 256, 0, stream>>>(Whh0, Whh0b, 4 * HH * HH / 4);
  cvt_f32_bf16<<<(4 * HH * HH / 4 + 255) / 256, 256, 0, stream>>>(Wih1, Wih1b, 4 * HH * HH / 4);
  cvt_f32_bf16<<<(4 * HH * HH / 4 + 255) / 256, 256, 0, stream>>>(Whh1, Whh1b, 4 * HH * HH / 4);
  cvt_f32_bf16<<<(VV * HH / 4 + 255) / 256, 256, 0, stream>>>(out_w, outwb, VV * HH / 4);
  hipMemsetAsync(e, 0, (size_t)BB * SS * 4, stream);

  // ---- t2 = hidden[1] @ W ----
  gemm_bt<0, 0><<<dim3(BB / 128, HH / 128), 256, 0, stream>>>(hlastb, Wt, t2, nullptr, HH, HH);

  // ---- scores e (fused t1 GEMM + tanh + Vw-dot) ----
  gemm_score<<<dim3(BB * SS / 128, HH / 128), 256, 0, stream>>>(enc_b, Ut, t2, Vw, e, HH);

  // ---- softmax + context ----
  softmax64<<<BB / 4, 256, 0, stream>>>(e, a);
  ctx_kernel<<<BB * HH / 256, 256, 0, stream>>>(a, enc_b, ctf);

  // ---- x = concat(embed, ct) ----
  build_x<<<(BB * (EE + HH) + 255) / 256, 256, 0, stream>>>(ids, emb, ctf, xb);

  // ---- LSTM layer 0 ----
  gemm_bt<0, 0><<<dim3(BB / 128, 4 * HH / 128), 256, 0, stream>>>(xb, Wih0b, g, nullptr, 4 * HH, EE + HH);
  gemm_bt<1, 0><<<dim3(BB / 128, 4 * HH / 128), 256, 0, stream>>>(hid0b, Whh0b, g, nullptr, 4 * HH, HH);
  lstm_cell<<<BB * HH / 256, 256, 0, stream>>>(g, bih0, bhh0, cell, h_new, c_new, h0b);

  // ---- LSTM layer 1 ----
  gemm_bt<0, 0><<<dim3(BB / 128, 4 * HH / 128), 256, 0, stream>>>(h0b, Wih1b, g, nullptr, 4 * HH, HH);
  gemm_bt<1, 0><<<dim3(BB / 128, 4 * HH / 128), 256, 0, stream>>>(hlastb, Whh1b, g, nullptr, 4 * HH, HH);
  lstm_cell<<<BB * HH / 256, 256, 0, stream>>>(g, bih1, bhh1, cell + BB * HH,
                                               h_new + BB * HH, c_new + BB * HH, h1b);

  // ---- output projection ----
  gemm_bt<0, 1><<<dim3(BB / 128, VV / 128), 256, 0, stream>>>(h1b, outwb, out_logits, out_b, VV, HH);
}

// Round 2
// 304.643 us; speedup vs baseline: 1.2855x; 1.2855x over previous
//
#include <hip/hip_runtime.h>
#include <stdint.h>

// dims
#define BB 512
#define SS 64
#define HH 1024
#define EE 256
#define VV 128

typedef __attribute__((ext_vector_type(8))) short bf16x8;
typedef __attribute__((ext_vector_type(4))) float f32x4;

__device__ __forceinline__ unsigned short f2bf(float f) {
  unsigned int u = __float_as_uint(f);
  unsigned int r = (u + 0x7FFFu + ((u >> 16) & 1u)) >> 16;
  return (unsigned short)r;
}
__device__ __forceinline__ float bf2f(unsigned short h) {
  return __uint_as_float(((unsigned int)h) << 16);
}

__device__ __forceinline__ void gload_lds16(const void* g, void* l) {
  __builtin_amdgcn_global_load_lds(
      (const __attribute__((address_space(1))) unsigned int*)g,
      (__attribute__((address_space(3))) unsigned int*)l, 16, 0, 0);
}

// ---------------- conversion kernels ----------------
__global__ void cvt_f32_bf16(const float* __restrict__ in,
                             unsigned short* __restrict__ out, int n4) {
  int i = blockIdx.x * blockDim.x + threadIdx.x;
  if (i >= n4) return;
  float4 v = ((const float4*)in)[i];
  ushort4 o;
  o.x = f2bf(v.x); o.y = f2bf(v.y); o.z = f2bf(v.z); o.w = f2bf(v.w);
  ((ushort4*)out)[i] = o;
}

// out[c*R + r] = bf16(in[r*C + c])
__global__ void transpose_cvt(const float* __restrict__ in,
                              unsigned short* __restrict__ out, int R, int C) {
  __shared__ float tile[32][33];
  int bc = blockIdx.x * 32, br = blockIdx.y * 32;
  int tx = threadIdx.x & 31, ty = threadIdx.x >> 5;
#pragma unroll
  for (int i = 0; i < 32; i += 8)
    tile[ty + i][tx] = in[(long)(br + ty + i) * C + bc + tx];
  __syncthreads();
#pragma unroll
  for (int i = 0; i < 32; i += 8)
    out[(long)(bc + ty + i) * R + br + tx] = f2bf(tile[tx][ty + i]);
}

// concat-convert [Wih | Whh] -> bf16 [4096][Kcat] (Whh is always [4096][1024])
__global__ void build_wcat(const float* __restrict__ Wih, const float* __restrict__ Whh,
                           unsigned short* __restrict__ out, int Kih, int Kcat) {
  int i = blockIdx.x * 256 + threadIdx.x;
  int total = 4096 * Kcat / 4;
  if (i >= total) return;
  int k4 = (i * 4) % Kcat, n = (i * 4) / Kcat;
  float4 v;
  if (k4 < Kih) v = *(const float4*)(Wih + (long)n * Kih + k4);
  else          v = *(const float4*)(Whh + (long)n * 1024 + (k4 - Kih));
  ushort4 o;
  o.x = f2bf(v.x); o.y = f2bf(v.y); o.z = f2bf(v.z); o.w = f2bf(v.w);
  ((ushort4*)out)[i] = o;
}

// fill xcat0 [512][2304]: cols 0..255 = emb[ids], cols 1280..2303 = hidden[0]
__global__ void build_xcat0(const int* __restrict__ ids, const float* __restrict__ emb,
                            const float* __restrict__ hid0, unsigned short* __restrict__ x) {
  int i = blockIdx.x * 256 + threadIdx.x;  // 512*1280
  if (i < 512 * 256) {
    int b = i >> 8, c = i & 255;
    x[(long)b * 2304 + c] = f2bf(emb[ids[b] * 256 + c]);
  } else {
    int j = i - 512 * 256;
    int b = j >> 10, c = j & 1023;
    x[(long)b * 2304 + 1280 + c] = f2bf(hid0[(long)b * 1024 + c]);
  }
}

// fill xcat1 [512][2048] cols 1024..2047 = hidden[1]
__global__ void fill_xcat1_h(const float* __restrict__ hid1, unsigned short* __restrict__ x) {
  int i = blockIdx.x * 256 + threadIdx.x;  // 512*1024
  int b = i >> 10, c = i & 1023;
  x[(long)b * 2048 + 1024 + c] = f2bf(hid1[i]);
}

// ---------------- generic bf16 MFMA GEMM (128x128 tile): C = A(MxK) * Bt(NxK)^T ----------------
template <int BIAS>
__global__ __launch_bounds__(256) void gemm_bt(
    const unsigned short* __restrict__ A, const unsigned short* __restrict__ Bt,
    float* __restrict__ C, const float* __restrict__ bias, int N, int K) {
  __shared__ alignas(128) unsigned short lA[128 * 64];
  __shared__ alignas(128) unsigned short lB[128 * 64];
  const int tid = threadIdx.x;
  const int lane = tid & 63, wid = tid >> 6;
  const int wr = wid >> 1, wc = wid & 1;
  const int fr = lane & 15, fg = lane >> 4;
  f32x4 acc[4][4] = {};
  const long rowA0 = (long)blockIdx.x * 128;
  const long rowB0 = (long)blockIdx.y * 128;
  for (int kt = 0; kt < K; kt += 64) {
#pragma unroll
    for (int j = 0; j < 4; ++j) {
      int c = j * 256 + tid;
      int r = c >> 3, cc = c & 7;
      gload_lds16(A + (rowA0 + r) * K + kt + cc * 8, &lA[c * 8]);
    }
#pragma unroll
    for (int j = 0; j < 4; ++j) {
      int c = j * 256 + tid;
      int r = c >> 3, cc = c & 7;
      gload_lds16(Bt + (rowB0 + r) * K + kt + cc * 8, &lB[c * 8]);
    }
    __syncthreads();
#pragma unroll
    for (int kk = 0; kk < 64; kk += 32) {
      bf16x8 af[4], bfv[4];
#pragma unroll
      for (int m = 0; m < 4; ++m)
        af[m] = *(const bf16x8*)&lA[(wr * 64 + m * 16 + fr) * 64 + kk + fg * 8];
#pragma unroll
      for (int n = 0; n < 4; ++n)
        bfv[n] = *(const bf16x8*)&lB[(wc * 64 + n * 16 + fr) * 64 + kk + fg * 8];
#pragma unroll
      for (int m = 0; m < 4; ++m)
#pragma unroll
        for (int n = 0; n < 4; ++n)
          acc[m][n] = __builtin_amdgcn_mfma_f32_16x16x32_bf16(af[m], bfv[n],
                                                              acc[m][n], 0, 0, 0);
    }
    __syncthreads();
  }
#pragma unroll
  for (int m = 0; m < 4; ++m)
#pragma unroll
    for (int n = 0; n < 4; ++n)
#pragma unroll
      for (int r = 0; r < 4; ++r) {
        long grow = rowA0 + wr * 64 + m * 16 + fg * 4 + r;
        long gcol = rowB0 + wc * 64 + n * 16 + fr;
        float v = acc[m][n][r];
        if (BIAS) v += bias[gcol];
        C[grow * N + gcol] = v;
      }
}

// ---------------- out projection, split-K, atomic accumulate ----------------
__global__ __launch_bounds__(256) void gemm_outproj(
    const unsigned short* __restrict__ A, const unsigned short* __restrict__ Bt,
    float* __restrict__ C) {
  __shared__ alignas(128) unsigned short lA[128 * 64];
  __shared__ alignas(128) unsigned short lB[128 * 64];
  const int tid = threadIdx.x;
  const int lane = tid & 63, wid = tid >> 6;
  const int wr = wid >> 1, wc = wid & 1;
  const int fr = lane & 15, fg = lane >> 4;
  f32x4 acc[4][4] = {};
  const long rowA0 = (long)blockIdx.x * 128;
  const int k0 = blockIdx.y * 128;  // 8 splits of 128
  for (int kt = k0; kt < k0 + 128; kt += 64) {
#pragma unroll
    for (int j = 0; j < 4; ++j) {
      int c = j * 256 + tid;
      int r = c >> 3, cc = c & 7;
      gload_lds16(A + (rowA0 + r) * 1024 + kt + cc * 8, &lA[c * 8]);
    }
#pragma unroll
    for (int j = 0; j < 4; ++j) {
      int c = j * 256 + tid;
      int r = c >> 3, cc = c & 7;
      gload_lds16(Bt + (long)r * 1024 + kt + cc * 8, &lB[c * 8]);
    }
    __syncthreads();
#pragma unroll
    for (int kk = 0; kk < 64; kk += 32) {
      bf16x8 af[4], bfv[4];
#pragma unroll
      for (int m = 0; m < 4; ++m)
        af[m] = *(const bf16x8*)&lA[(wr * 64 + m * 16 + fr) * 64 + kk + fg * 8];
#pragma unroll
      for (int n = 0; n < 4; ++n)
        bfv[n] = *(const bf16x8*)&lB[(wc * 64 + n * 16 + fr) * 64 + kk + fg * 8];
#pragma unroll
      for (int m = 0; m < 4; ++m)
#pragma unroll
        for (int n = 0; n < 4; ++n)
          acc[m][n] = __builtin_amdgcn_mfma_f32_16x16x32_bf16(af[m], bfv[n],
                                                              acc[m][n], 0, 0, 0);
    }
    __syncthreads();
  }
#pragma unroll
  for (int m = 0; m < 4; ++m)
#pragma unroll
    for (int n = 0; n < 4; ++n)
#pragma unroll
      for (int r = 0; r < 4; ++r) {
        long grow = rowA0 + wr * 64 + m * 16 + fg * 4 + r;
        long gcol = wc * 64 + n * 16 + fr;
        atomicAdd(&C[grow * 128 + gcol], acc[m][n][r]);
      }
}

__global__ void init_out_bias(const float* __restrict__ ob, float* __restrict__ out) {
  int i = blockIdx.x * 256 + threadIdx.x;  // 512*128
  out[i] = ob[i & 127];
}

// ---------------- 256x256 8-phase score GEMM (T2+T3+T4+T5) ----------------
// A[32768][K] bf16, Bt[1024][K] bf16 -> e[row] += sum_col tanh(acc + t2[b,col]) * Vw[col]
// LDS: 2 bufs x 4 regions (A.k0,B.k0,A.k1,B.k1), each region [256 rows][32 k] bf16 = 16KB,
// chunk-swizzled: 16B slot s at row r holds k-chunk (s ^ ((r>>1)&3)).
__global__ __launch_bounds__(512, 2) void gemm_score256(
    const unsigned short* __restrict__ A, const unsigned short* __restrict__ Bt,
    const float* __restrict__ t2, const float* __restrict__ Vw,
    float* __restrict__ e, int K) {
  extern __shared__ unsigned short smem[];  // [2][4][8192]
  const int tid = threadIdx.x;
  const int lane = tid & 63, wid = tid >> 6;
  const int wr = wid >> 2;       // 0..1  (M half: 128 rows)
  const int wcc = wid & 3;       // 0..3  (N quarter: 64 cols)
  const int fr = lane & 15, fg = lane >> 4;
  const long rowA0 = (long)blockIdx.y * 256;
  const long rowB0 = (long)blockIdx.x * 256;
  const int NKT = K >> 6, NIT = NKT >> 1;

  f32x4 acc[8][4] = {};

  auto RA = [&](int buf, int kh) { return (const unsigned short*)(smem + (buf * 4 + kh * 2) * 8192); };
  auto RB = [&](int buf, int kh) { return (const unsigned short*)(smem + (buf * 4 + kh * 2 + 1) * 8192); };

  auto stage = [&](int buf, int reg, int ktile) {
    const unsigned short* base = (reg & 1) ? Bt : A;
    long r0 = (reg & 1) ? rowB0 : rowA0;
    int kb = ktile * 64 + (reg >> 1) * 32;
    unsigned short* dst = smem + (buf * 4 + reg) * 8192;
#pragma unroll
    for (int j = 0; j < 2; ++j) {
      int c = j * 512 + tid;
      int row = c >> 2;
      int fgl = (c & 3) ^ ((row >> 1) & 3);
      gload_lds16(base + (r0 + row) * (long)K + kb + fgl * 8, dst + c * 8);
    }
  };
  auto readA = [&](const unsigned short* rg, int mh, bf16x8* af) {
#pragma unroll
    for (int m = 0; m < 4; ++m) {
      int row = wr * 128 + mh * 64 + m * 16 + fr;
      int slot = fg ^ ((row >> 1) & 3);
      af[m] = *(const bf16x8*)(rg + row * 32 + slot * 8);
    }
  };
  auto readB = [&](const unsigned short* rg, bf16x8* bv) {
#pragma unroll
    for (int n = 0; n < 4; ++n) {
      int row = wcc * 64 + n * 16 + fr;
      int slot = fg ^ ((row >> 1) & 3);
      bv[n] = *(const bf16x8*)(rg + row * 32 + slot * 8);
    }
  };
  auto mfma16 = [&](int mh, const bf16x8* af, const bf16x8* bv) {
    __builtin_amdgcn_s_setprio(1);
#pragma unroll
    for (int m = 0; m < 4; ++m)
#pragma unroll
      for (int n = 0; n < 4; ++n)
        acc[mh * 4 + m][n] = __builtin_amdgcn_mfma_f32_16x16x32_bf16(
            af[m], bv[n], acc[mh * 4 + m][n], 0, 0, 0);
    __builtin_amdgcn_s_setprio(0);
  };

#define BAR() __builtin_amdgcn_s_barrier()
#define WAIT6() asm volatile("s_waitcnt vmcnt(6)" ::: "memory")

  // prologue: buf0 all 4 regions (K-tile 0), buf1 k0 regions (K-tile 1)
  stage(0, 0, 0); stage(0, 1, 0); stage(0, 2, 0); stage(0, 3, 0);
  stage(1, 0, 1); stage(1, 1, 1);
  asm volatile("s_waitcnt vmcnt(8)" ::: "memory");
  BAR();

  for (int t = 0; t < NIT; ++t) {
    int k1 = 2 * t + 1, k2 = 2 * t + 2, k3 = 2 * t + 3;
    if (k2 >= NKT) k2 -= NKT;   // wrapped dead stages keep vmcnt counts exact
    if (k3 >= NKT) k3 -= NKT;
    bf16x8 af[4], bv[4];
    // p1: buf0.k0 first read
    readB(RB(0, 0), bv); readA(RA(0, 0), 0, af);
    stage(1, 2, k1);
    BAR(); mfma16(0, af, bv); BAR();
    // p2
    WAIT6();
    readA(RA(0, 0), 1, af);
    stage(1, 3, k1);
    BAR(); mfma16(1, af, bv); BAR();
    // p3: buf0.k1 first read
    readB(RB(0, 1), bv); readA(RA(0, 1), 0, af);
    stage(0, 0, k2);
    BAR(); mfma16(0, af, bv); BAR();
    // p4
    WAIT6();
    readA(RA(0, 1), 1, af);
    stage(0, 1, k2);
    BAR(); mfma16(1, af, bv); BAR();
    // p5: buf1.k0 first read
    readB(RB(1, 0), bv); readA(RA(1, 0), 0, af);
    stage(0, 2, k2);
    BAR(); mfma16(0, af, bv); BAR();
    // p6
    WAIT6();
    readA(RA(1, 0), 1, af);
    stage(0, 3, k2);
    BAR(); mfma16(1, af, bv); BAR();
    // p7: buf1.k1 first read
    readB(RB(1, 1), bv); readA(RA(1, 1), 0, af);
    stage(1, 0, k3);
    BAR(); mfma16(0, af, bv); BAR();
    // p8
    WAIT6();
    readA(RA(1, 1), 1, af);
    stage(1, 1, k3);
    BAR(); mfma16(1, af, bv); BAR();
  }
  asm volatile("s_waitcnt vmcnt(0)" ::: "memory");

  // epilogue: e[row] += sum over this block's 256 cols of tanh(acc + t2)*Vw
  float t2v[2][4], vw[4];
#pragma unroll
  for (int n = 0; n < 4; ++n) {
    long col = rowB0 + wcc * 64 + n * 16 + fr;
    vw[n] = Vw[col];
#pragma unroll
    for (int h = 0; h < 2; ++h) {
      long b = (rowA0 >> 6) + wr * 2 + h;
      t2v[h][n] = t2[b * HH + col];
    }
  }
#pragma unroll
  for (int i = 0; i < 8; ++i) {
    int hsel = i >> 2;
    float part[4] = {0.f, 0.f, 0.f, 0.f};
#pragma unroll
    for (int n = 0; n < 4; ++n) {
#pragma unroll
      for (int r = 0; r < 4; ++r) {
        float tval = acc[i][n][r] + t2v[hsel][n];
        float th = 1.f - 2.f / (__expf(2.f * tval) + 1.f);
        part[r] += th * vw[n];
      }
    }
#pragma unroll
    for (int r = 0; r < 4; ++r) {
      float p = part[r];
      p += __shfl_xor(p, 1);
      p += __shfl_xor(p, 2);
      p += __shfl_xor(p, 4);
      p += __shfl_xor(p, 8);
      if (fr == 0)
        atomicAdd(&e[rowA0 + wr * 128 + i * 16 + fg * 4 + r], p);
    }
  }
#undef BAR
#undef WAIT6
}

// ---------------- softmax over S=64, one wave per batch row ----------------
__global__ void softmax64(const float* __restrict__ e, float* __restrict__ a) {
  int b = blockIdx.x * 4 + (threadIdx.x >> 6);
  int s = threadIdx.x & 63;
  float v = e[b * 64 + s];
  float mx = v;
#pragma unroll
  for (int o = 32; o; o >>= 1) mx = fmaxf(mx, __shfl_xor(mx, o));
  float ex = __expf(v - mx);
  float sm = ex;
#pragma unroll
  for (int o = 32; o; o >>= 1) sm += __shfl_xor(sm, o);
  a[b * 64 + s] = ex / sm;
}

// ---------------- context -> bf16 into xcat0 cols 256..1279 ----------------
__global__ void ctx_kernel(const float* __restrict__ a,
                           const unsigned short* __restrict__ encb,
                           unsigned short* __restrict__ xcat) {
  int idx = blockIdx.x * 256 + threadIdx.x;  // 512*1024
  int b = idx >> 10, h = idx & 1023;
  const float* ar = a + b * 64;
  const unsigned short* er = encb + (long)b * (SS * HH) + h;
  float s = 0.f;
#pragma unroll 8
  for (int i = 0; i < 64; ++i) s += ar[i] * bf2f(er[(long)i * HH]);
  xcat[(long)b * 2304 + 256 + h] = f2bf(s);
}

// ---------------- LSTM cell elementwise ----------------
__global__ void lstm_cell(const float* __restrict__ g, const float* __restrict__ bih,
                          const float* __restrict__ bhh, const float* __restrict__ cin,
                          float* __restrict__ hout, float* __restrict__ cout,
                          unsigned short* __restrict__ hb, int hb_stride) {
  int idx = blockIdx.x * 256 + threadIdx.x;  // 512*1024
  int b = idx >> 10, h = idx & 1023;
  const float* gr = g + (long)b * 4096;
  float gi = gr[h] + bih[h] + bhh[h];
  float gf = gr[1024 + h] + bih[1024 + h] + bhh[1024 + h];
  float gg = gr[2048 + h] + bih[2048 + h] + bhh[2048 + h];
  float go = gr[3072 + h] + bih[3072 + h] + bhh[3072 + h];
  float si = 1.f / (1.f + __expf(-gi));
  float sf = 1.f / (1.f + __expf(-gf));
  float so = 1.f / (1.f + __expf(-go));
  float tg = 1.f - 2.f / (__expf(2.f * gg) + 1.f);
  float c2 = sf * cin[idx] + si * tg;
  float tc = 1.f - 2.f / (__expf(2.f * c2) + 1.f);
  float h2 = so * tc;
  cout[idx] = c2;
  hout[idx] = h2;
  hb[(long)b * hb_stride + h] = f2bf(h2);
}

extern "C" void kernel_launch(void* const* d_in, const int* in_sizes, int n_in,
                              void* d_out, int out_size, void* d_ws, size_t ws_size,
                              hipStream_t stream) {
  const int* ids = (const int*)d_in[0];
  const float* hidden = (const float*)d_in[1];
  const float* cell = (const float*)d_in[2];
  const float* enc = (const float*)d_in[3];
  const float* emb = (const float*)d_in[4];
  const float* U = (const float*)d_in[5];
  const float* W = (const float*)d_in[6];
  const float* Vw = (const float*)d_in[7];
  const float* Wih0 = (const float*)d_in[8];
  const float* Whh0 = (const float*)d_in[9];
  const float* bih0 = (const float*)d_in[10];
  const float* bhh0 = (const float*)d_in[11];
  const float* Wih1 = (const float*)d_in[12];
  const float* Whh1 = (const float*)d_in[13];
  const float* bih1 = (const float*)d_in[14];
  const float* bhh1 = (const float*)d_in[15];
  const float* out_w = (const float*)d_in[16];
  const float* out_b = (const float*)d_in[17];
  float* out = (float*)d_out;

  char* ws = (char*)d_ws;
  size_t off = 0;
  auto alloc = [&](size_t bytes) {
    char* p = ws + off;
    off += (bytes + 255) & ~(size_t)255;
    return p;
  };
  unsigned short* enc_b = (unsigned short*)alloc((size_t)BB * SS * HH * 2);
  unsigned short* Ut = (unsigned short*)alloc((size_t)HH * HH * 2);
  unsigned short* Wt = (unsigned short*)alloc((size_t)HH * HH * 2);
  unsigned short* wcat0 = (unsigned short*)alloc((size_t)4096 * 2304 * 2);
  unsigned short* wcat1 = (unsigned short*)alloc((size_t)4096 * 2048 * 2);
  unsigned short* outwb = (unsigned short*)alloc((size_t)VV * HH * 2);
  unsigned short* hlastb = (unsigned short*)alloc((size_t)BB * HH * 2);
  float* t2 = (float*)alloc((size_t)BB * HH * 4);
  float* e = (float*)alloc((size_t)BB * SS * 4);
  float* a = (float*)alloc((size_t)BB * SS * 4);
  unsigned short* xcat0 = (unsigned short*)alloc((size_t)BB * 2304 * 2);
  unsigned short* xcat1 = (unsigned short*)alloc((size_t)BB * 2048 * 2);
  float* g = (float*)alloc((size_t)BB * 4 * HH * 4);
  unsigned short* h1b = (unsigned short*)alloc((size_t)BB * HH * 2);
  (void)ws_size; (void)in_sizes; (void)n_in; (void)out_size;

  float* out_logits = out;
  float* h_new = out + BB * VV;
  float* c_new = h_new + 2 * BB * HH;

  // ---- conversions ----
  cvt_f32_bf16<<<BB * SS * HH / 4 / 256, 256, 0, stream>>>(enc, enc_b, BB * SS * HH / 4);
  cvt_f32_bf16<<<BB * HH / 4 / 256, 256, 0, stream>>>(hidden + BB * HH, hlastb, BB * HH / 4);
  transpose_cvt<<<dim3(HH / 32, HH / 32), 256, 0, stream>>>(U, Ut, HH, HH);
  transpose_cvt<<<dim3(HH / 32, HH / 32), 256, 0, stream>>>(W, Wt, HH, HH);
  build_wcat<<<4096 * 2304 / 4 / 256, 256, 0, stream>>>(Wih0, Whh0, wcat0, 1280, 2304);
  build_wcat<<<4096 * 2048 / 4 / 256, 256, 0, stream>>>(Wih1, Whh1, wcat1, 1024, 2048);
  cvt_f32_bf16<<<VV * HH / 4 / 256, 256, 0, stream>>>(out_w, outwb, VV * HH / 4);
  build_xcat0<<<512 * 1280 / 256, 256, 0, stream>>>(ids, emb, hidden, xcat0);
  fill_xcat1_h<<<512 * 1024 / 256, 256, 0, stream>>>(hidden + BB * HH, xcat1);
  hipMemsetAsync(e, 0, (size_t)BB * SS * 4, stream);

  // ---- t2 = hidden[1] @ W ----
  gemm_bt<0><<<dim3(BB / 128, HH / 128), 256, 0, stream>>>(hlastb, Wt, t2, nullptr, HH, HH);

  // ---- scores e (256^2 8-phase fused GEMM) ----
  (void)hipFuncSetAttribute(reinterpret_cast<const void*>(gemm_score256),
                            hipFuncAttributeMaxDynamicSharedMemorySize, 131072);
  gemm_score256<<<dim3(HH / 256, BB * SS / 256), 512, 131072, stream>>>(
      enc_b, Ut, t2, Vw, e, HH);

  // ---- softmax + context (ctx writes bf16 into xcat0) ----
  softmax64<<<BB / 4, 256, 0, stream>>>(e, a);
  ctx_kernel<<<BB * HH / 256, 256, 0, stream>>>(a, enc_b, xcat0);

  // ---- LSTM layer 0: g = [x|h0] @ [Wih0|Whh0]^T ----
  gemm_bt<0><<<dim3(BB / 128, 4 * HH / 128), 256, 0, stream>>>(xcat0, wcat0, g, nullptr, 4 * HH, 2304);
  lstm_cell<<<BB * HH / 256, 256, 0, stream>>>(g, bih0, bhh0, cell, h_new, c_new, xcat1, 2048);

  // ---- LSTM layer 1: g = [h0|h1prev] @ [Wih1|Whh1]^T ----
  gemm_bt<0><<<dim3(BB / 128, 4 * HH / 128), 256, 0, stream>>>(xcat1, wcat1, g, nullptr, 4 * HH, 2048);
  lstm_cell<<<BB * HH / 256, 256, 0, stream>>>(g, bih1, bhh1, cell + BB * HH,
                                               h_new + BB * HH, c_new + BB * HH, h1b, 1024);

  // ---- output projection (split-K + bias init) ----
  init_out_bias<<<BB * VV / 256, 256, 0, stream>>>(out_b, out_logits);
  gemm_outproj<<<dim3(BB / 128, 8), 256, 0, stream>>>(h1b, outwb, out_logits);
}

// Round 3
// 256.907 us; speedup vs baseline: 1.5244x; 1.1858x over previous
//
#include <hip/hip_runtime.h>
#include <stdint.h>

// dims
#define BB 512
#define SS 64
#define HH 1024
#define EE 256
#define VV 128

typedef __attribute__((ext_vector_type(8))) short bf16x8;
typedef __attribute__((ext_vector_type(4))) float f32x4;

// ---- workspace layout (bytes, all 256-aligned) ----
constexpr size_t OFF_ENC   = 0;                           // 32768x1024 bf16 = 64MB
constexpr size_t OFF_WIH0  = OFF_ENC   + 67108864UL;      // 4096x1280 bf16
constexpr size_t OFF_WHH0  = OFF_WIH0  + 10485760UL;      // 4096x1024 bf16
constexpr size_t OFF_WIH1  = OFF_WHH0  + 8388608UL;       // 4096x1024 bf16
constexpr size_t OFF_WHH1  = OFF_WIH1  + 8388608UL;       // 4096x1024 bf16
constexpr size_t OFF_OUTW  = OFF_WHH1  + 8388608UL;       // 128x1024 bf16
constexpr size_t OFF_HID0  = OFF_OUTW  + 262144UL;        // 512x1024 bf16 (input hidden[0])
constexpr size_t OFF_HLAST = OFF_HID0  + 1048576UL;       // 512x1024 bf16 (input hidden[1])
constexpr size_t OFF_UT    = OFF_HLAST + 1048576UL;       // 1024x1024 bf16 (U^T)
constexpr size_t OFF_WT    = OFF_UT    + 2097152UL;       // 1024x1024 bf16 (W^T)
constexpr size_t OFF_T2    = OFF_WT    + 2097152UL;       // 512x1024 f32
constexpr size_t OFF_E     = OFF_T2    + 2097152UL;       // 512x64 f32
constexpr size_t OFF_EMB   = OFF_E     + 131072UL;        // 512x256 bf16
constexpr size_t OFF_CT    = OFF_EMB   + 262144UL;        // 512x1024 bf16
constexpr size_t OFF_G     = OFF_CT    + 1048576UL;       // 512x4096 f32
constexpr size_t OFF_H0B   = OFF_G     + 8388608UL;       // 512x1024 bf16 (lstm0 out)
constexpr size_t OFF_H1B   = OFF_H0B   + 1048576UL;       // 512x1024 bf16 (lstm1 out)

__device__ __forceinline__ unsigned short f2bf(float f) {
  unsigned int u = __float_as_uint(f);
  unsigned int r = (u + 0x7FFFu + ((u >> 16) & 1u)) >> 16;
  return (unsigned short)r;
}
__device__ __forceinline__ float bf2f(unsigned short h) {
  return __uint_as_float(((unsigned int)h) << 16);
}

__device__ __forceinline__ void gload_lds16(const void* g, void* l) {
  __builtin_amdgcn_global_load_lds(
      (const __attribute__((address_space(1))) unsigned int*)g,
      (__attribute__((address_space(3))) unsigned int*)l, 16, 0, 0);
}

// ---------------- merged straight f32->bf16 conversion (grid-stride) ----------------
__global__ void cvt_all(const float* __restrict__ enc, const float* __restrict__ Wih0,
                        const float* __restrict__ Whh0, const float* __restrict__ Wih1,
                        const float* __restrict__ Whh1, const float* __restrict__ outw,
                        const float* __restrict__ hid, char* __restrict__ ws) {
  // segment sizes in float4 units (cumulative):
  // enc 8388608 | wih0 1310720 | whh0 1048576 | wih1 1048576 | whh1 1048576
  // | outw 32768 | hid0 131072 | hlast 131072   total 13139968
  long i = (long)blockIdx.x * 256 + threadIdx.x;
  const long stride = (long)gridDim.x * 256;
  for (; i < 13139968L; i += stride) {
    const float4* src; ushort4* dst; long j;
    if (i < 8388608L)       { src = (const float4*)enc;  dst = (ushort4*)(ws + OFF_ENC);  j = i; }
    else if (i < 9699328L)  { src = (const float4*)Wih0; dst = (ushort4*)(ws + OFF_WIH0); j = i - 8388608L; }
    else if (i < 10747904L) { src = (const float4*)Whh0; dst = (ushort4*)(ws + OFF_WHH0); j = i - 9699328L; }
    else if (i < 11796480L) { src = (const float4*)Wih1; dst = (ushort4*)(ws + OFF_WIH1); j = i - 10747904L; }
    else if (i < 12845056L) { src = (const float4*)Whh1; dst = (ushort4*)(ws + OFF_WHH1); j = i - 11796480L; }
    else if (i < 12877824L) { src = (const float4*)outw; dst = (ushort4*)(ws + OFF_OUTW); j = i - 12845056L; }
    else if (i < 13008896L) { src = (const float4*)hid;  dst = (ushort4*)(ws + OFF_HID0); j = i - 12877824L; }
    else { src = (const float4*)(hid + 524288); dst = (ushort4*)(ws + OFF_HLAST); j = i - 13008896L; }
    float4 v = src[j];
    ushort4 o;
    o.x = f2bf(v.x); o.y = f2bf(v.y); o.z = f2bf(v.z); o.w = f2bf(v.w);
    dst[j] = o;
  }
}

// ---------------- transpose-convert U and W (z selects) ----------------
__global__ void transpose_cvt2(const float* __restrict__ U, const float* __restrict__ W,
                               char* __restrict__ ws) {
  __shared__ float tile[32][33];
  const float* in = blockIdx.z ? W : U;
  unsigned short* out = (unsigned short*)(ws + (blockIdx.z ? OFF_WT : OFF_UT));
  int bc = blockIdx.x * 32, br = blockIdx.y * 32;
  int tx = threadIdx.x & 31, ty = threadIdx.x >> 5;
#pragma unroll
  for (int i = 0; i < 32; i += 8)
    tile[ty + i][tx] = in[(long)(br + ty + i) * HH + bc + tx];
  __syncthreads();
#pragma unroll
  for (int i = 0; i < 32; i += 8)
    out[(long)(bc + ty + i) * HH + br + tx] = f2bf(tile[tx][ty + i]);
}

// ---------------- embedded token gather -> bf16 ----------------
__global__ void build_xemb(const int* __restrict__ ids, const float* __restrict__ emb,
                           unsigned short* __restrict__ embb) {
  int t = blockIdx.x * 256 + threadIdx.x;  // 32768 = 512 * 64 float4s
  int b = t >> 6, c4 = t & 63;
  float4 v = ((const float4*)(emb + (long)ids[b] * 256))[c4];
  ushort4 o;
  o.x = f2bf(v.x); o.y = f2bf(v.y); o.z = f2bf(v.z); o.w = f2bf(v.w);
  ((ushort4*)embb)[t] = o;
}

// ---------------- segmented bf16 GEMM: C = A(512 x Ktot) * Bt(N x Ktot)^T ----------------
// BM=128, BN=64, 256 threads (4 waves 2x2, wave tile 64x32). A up to 3 K-segments, B up to 2.
__global__ __launch_bounds__(256) void gemm_seg(
    const unsigned short* __restrict__ A0, int KA0,
    const unsigned short* __restrict__ A1, int KA1,
    const unsigned short* __restrict__ A2,
    const unsigned short* __restrict__ B0, int KB0,
    const unsigned short* __restrict__ B1,
    float* __restrict__ C, int N, int Ktot) {
  __shared__ alignas(128) unsigned short lA[128 * 64];
  __shared__ alignas(128) unsigned short lB[64 * 64];
  const int tid = threadIdx.x;
  const int lane = tid & 63, wid = tid >> 6;
  const int wr = wid >> 1, wc = wid & 1;
  const int fr = lane & 15, fg = lane >> 4;
  f32x4 acc[4][2] = {};
  const long rowA0 = (long)blockIdx.x * 128;
  const long rowB0 = (long)blockIdx.y * 64;
  for (int kt = 0; kt < Ktot; kt += 64) {
    const unsigned short* Ap; int ka, lda;
    if (kt < KA0)            { Ap = A0; ka = kt;             lda = KA0; }
    else if (kt < KA0 + KA1) { Ap = A1; ka = kt - KA0;       lda = KA1; }
    else                     { Ap = A2; ka = kt - KA0 - KA1; lda = 1024; }
    const unsigned short* Bp; int kb, ldb;
    if (kt < KB0) { Bp = B0; kb = kt;       ldb = KB0; }
    else          { Bp = B1; kb = kt - KB0; ldb = 1024; }
    // stage with 3-bit chunk XOR swizzle (involution applied on global source)
#pragma unroll
    for (int j = 0; j < 4; ++j) {
      int c = j * 256 + tid;
      int r = c >> 3, cc = c & 7;
      int sc = cc ^ ((r >> 1) & 7);
      gload_lds16(Ap + (rowA0 + r) * (long)lda + ka + sc * 8, &lA[c * 8]);
    }
#pragma unroll
    for (int j = 0; j < 2; ++j) {
      int c = j * 256 + tid;
      int r = c >> 3, cc = c & 7;
      int sc = cc ^ ((r >> 1) & 7);
      gload_lds16(Bp + (rowB0 + r) * (long)ldb + kb + sc * 8, &lB[c * 8]);
    }
    __syncthreads();
#pragma unroll
    for (int kk = 0; kk < 64; kk += 32) {
      bf16x8 af[4], bfv[2];
#pragma unroll
      for (int m = 0; m < 4; ++m) {
        int row = wr * 64 + m * 16 + fr;
        int ch = ((kk >> 3) + fg) ^ ((row >> 1) & 7);
        af[m] = *(const bf16x8*)&lA[row * 64 + ch * 8];
      }
#pragma unroll
      for (int n = 0; n < 2; ++n) {
        int row = wc * 32 + n * 16 + fr;
        int ch = ((kk >> 3) + fg) ^ ((row >> 1) & 7);
        bfv[n] = *(const bf16x8*)&lB[row * 64 + ch * 8];
      }
#pragma unroll
      for (int m = 0; m < 4; ++m)
#pragma unroll
        for (int n = 0; n < 2; ++n)
          acc[m][n] = __builtin_amdgcn_mfma_f32_16x16x32_bf16(af[m], bfv[n],
                                                              acc[m][n], 0, 0, 0);
    }
    __syncthreads();
  }
#pragma unroll
  for (int m = 0; m < 4; ++m)
#pragma unroll
    for (int n = 0; n < 2; ++n)
#pragma unroll
      for (int r = 0; r < 4; ++r) {
        long grow = rowA0 + wr * 64 + m * 16 + fg * 4 + r;
        long gcol = rowB0 + wc * 32 + n * 16 + fr;
        C[grow * N + gcol] = acc[m][n][r];
      }
}

// ---------------- out projection, split-K, atomic accumulate ----------------
__global__ __launch_bounds__(256) void gemm_outproj(
    const unsigned short* __restrict__ A, const unsigned short* __restrict__ Bt,
    float* __restrict__ C) {
  __shared__ alignas(128) unsigned short lA[128 * 64];
  __shared__ alignas(128) unsigned short lB[128 * 64];
  const int tid = threadIdx.x;
  const int lane = tid & 63, wid = tid >> 6;
  const int wr = wid >> 1, wc = wid & 1;
  const int fr = lane & 15, fg = lane >> 4;
  f32x4 acc[4][4] = {};
  const long rowA0 = (long)blockIdx.x * 128;
  const int k0 = blockIdx.y * 128;
  for (int kt = k0; kt < k0 + 128; kt += 64) {
#pragma unroll
    for (int j = 0; j < 4; ++j) {
      int c = j * 256 + tid;
      int r = c >> 3, cc = c & 7;
      gload_lds16(A + (rowA0 + r) * 1024 + kt + cc * 8, &lA[c * 8]);
    }
#pragma unroll
    for (int j = 0; j < 4; ++j) {
      int c = j * 256 + tid;
      int r = c >> 3, cc = c & 7;
      gload_lds16(Bt + (long)r * 1024 + kt + cc * 8, &lB[c * 8]);
    }
    __syncthreads();
#pragma unroll
    for (int kk = 0; kk < 64; kk += 32) {
      bf16x8 af[4], bfv[4];
#pragma unroll
      for (int m = 0; m < 4; ++m)
        af[m] = *(const bf16x8*)&lA[(wr * 64 + m * 16 + fr) * 64 + kk + fg * 8];
#pragma unroll
      for (int n = 0; n < 4; ++n)
        bfv[n] = *(const bf16x8*)&lB[(wc * 64 + n * 16 + fr) * 64 + kk + fg * 8];
#pragma unroll
      for (int m = 0; m < 4; ++m)
#pragma unroll
        for (int n = 0; n < 4; ++n)
          acc[m][n] = __builtin_amdgcn_mfma_f32_16x16x32_bf16(af[m], bfv[n],
                                                              acc[m][n], 0, 0, 0);
    }
    __syncthreads();
  }
#pragma unroll
  for (int m = 0; m < 4; ++m)
#pragma unroll
    for (int n = 0; n < 4; ++n)
#pragma unroll
      for (int r = 0; r < 4; ++r) {
        long grow = rowA0 + wr * 64 + m * 16 + fg * 4 + r;
        long gcol = wc * 64 + n * 16 + fr;
        atomicAdd(&C[grow * 128 + gcol], acc[m][n][r]);
      }
}

__global__ void init_out_bias(const float* __restrict__ ob, float* __restrict__ out) {
  int i = blockIdx.x * 256 + threadIdx.x;
  out[i] = ob[i & 127];
}

// ---------------- 256x256 8-phase score GEMM with reg-prefetch + XCD swizzle ----------------
__global__ __launch_bounds__(512, 2) void gemm_score256(
    const unsigned short* __restrict__ A, const unsigned short* __restrict__ Bt,
    const float* __restrict__ t2, const float* __restrict__ Vw,
    float* __restrict__ e) {
  extern __shared__ unsigned short smem[];  // [2][4][8192]
  const int K = HH;
  const int tid = threadIdx.x;
  const int lane = tid & 63, wid = tid >> 6;
  const int wr = wid >> 2;       // M half (128 rows)
  const int wcc = wid & 3;       // N quarter (64 cols)
  const int fr = lane & 15, fg = lane >> 4;
  // T1: chunked XCD swizzle (512 blocks = 8 xcd-chunks x 64)
  int flat = blockIdx.y * 4 + blockIdx.x;
  int swz = (flat & 7) * 64 + (flat >> 3);
  const long rowA0 = (long)(swz >> 2) * 256;
  const long rowB0 = (long)(swz & 3) * 256;
  const int NKT = 16, NIT = 8;

  f32x4 acc[8][4] = {};

  auto RA = [&](int buf, int kh) { return (const unsigned short*)(smem + (buf * 4 + kh * 2) * 8192); };
  auto RB = [&](int buf, int kh) { return (const unsigned short*)(smem + (buf * 4 + kh * 2 + 1) * 8192); };

  auto stage = [&](int buf, int reg, int ktile) {
    const unsigned short* base = (reg & 1) ? Bt : A;
    long r0 = (reg & 1) ? rowB0 : rowA0;
    int kb = ktile * 64 + (reg >> 1) * 32;
    unsigned short* dst = smem + (buf * 4 + reg) * 8192;
#pragma unroll
    for (int j = 0; j < 2; ++j) {
      int c = j * 512 + tid;
      int row = c >> 2;
      int fgl = (c & 3) ^ ((row >> 1) & 3);
      gload_lds16(base + (r0 + row) * (long)K + kb + fgl * 8, dst + c * 8);
    }
  };
  auto readA = [&](const unsigned short* rg, int mh, bf16x8* af) {
#pragma unroll
    for (int m = 0; m < 4; ++m) {
      int row = wr * 128 + mh * 64 + m * 16 + fr;
      int slot = fg ^ ((row >> 1) & 3);
      af[m] = *(const bf16x8*)(rg + row * 32 + slot * 8);
    }
  };
  auto readB = [&](const unsigned short* rg, bf16x8* bv) {
#pragma unroll
    for (int n = 0; n < 4; ++n) {
      int row = wcc * 64 + n * 16 + fr;
      int slot = fg ^ ((row >> 1) & 3);
      bv[n] = *(const bf16x8*)(rg + row * 32 + slot * 8);
    }
  };
  auto mfma16 = [&](int mh, const bf16x8* af, const bf16x8* bv) {
    __builtin_amdgcn_s_setprio(1);
#pragma unroll
    for (int m = 0; m < 4; ++m)
#pragma unroll
      for (int n = 0; n < 4; ++n)
        acc[mh * 4 + m][n] = __builtin_amdgcn_mfma_f32_16x16x32_bf16(
            af[m], bv[n], acc[mh * 4 + m][n], 0, 0, 0);
    __builtin_amdgcn_s_setprio(0);
  };

#define BAR() __builtin_amdgcn_s_barrier()
#define WAIT6() asm volatile("s_waitcnt vmcnt(6)" ::: "memory")

  bf16x8 afA[4], afB[4], bvA[4], bvB[4];

  // prologue: buf0 all 4 regions (K-tile 0), buf1 k0 regions (K-tile 1)
  stage(0, 0, 0); stage(0, 1, 0); stage(0, 2, 0); stage(0, 3, 0);
  stage(1, 0, 1); stage(1, 1, 1);
  asm volatile("s_waitcnt vmcnt(8)" ::: "memory");
  BAR();
  readA(RA(0, 0), 0, afA); readB(RB(0, 0), bvA);   // frags for p1

  for (int t = 0; t < NIT; ++t) {
    int k1 = 2 * t + 1, k2 = 2 * t + 2, k3 = 2 * t + 3;
    if (k2 >= NKT) k2 -= NKT;
    if (k3 >= NKT) k3 -= NKT;
    // p1: compute buf0.k0 mh0; prefetch buf0.k0 mh1
    readA(RA(0, 0), 1, afB);
    stage(1, 2, k1);
    BAR(); mfma16(0, afA, bvA); BAR();
    // p2: compute buf0.k0 mh1; prefetch buf0.k1 mh0 + B
    WAIT6();
    readA(RA(0, 1), 0, afA); readB(RB(0, 1), bvB);
    stage(1, 3, k1);
    BAR(); mfma16(1, afB, bvA); BAR();
    // p3
    readA(RA(0, 1), 1, afB);
    stage(0, 0, k2);
    BAR(); mfma16(0, afA, bvB); BAR();
    // p4
    WAIT6();
    readA(RA(1, 0), 0, afA); readB(RB(1, 0), bvA);
    stage(0, 1, k2);
    BAR(); mfma16(1, afB, bvB); BAR();
    // p5
    readA(RA(1, 0), 1, afB);
    stage(0, 2, k2);
    BAR(); mfma16(0, afA, bvA); BAR();
    // p6
    WAIT6();
    readA(RA(1, 1), 0, afA); readB(RB(1, 1), bvB);
    stage(0, 3, k2);
    BAR(); mfma16(1, afB, bvA); BAR();
    // p7
    readA(RA(1, 1), 1, afB);
    stage(1, 0, k3);
    BAR(); mfma16(0, afA, bvB); BAR();
    // p8: prefetch next iter's p1 (buf0.k0, freshly staged at p3/p4)
    WAIT6();
    readA(RA(0, 0), 0, afA); readB(RB(0, 0), bvA);
    stage(1, 1, k3);
    BAR(); mfma16(1, afB, bvB); BAR();
  }
  asm volatile("s_waitcnt vmcnt(0)" ::: "memory");

  // epilogue: e[row] += sum over this block's 256 cols of tanh(acc + t2)*Vw
  float t2v[2][4], vw[4];
#pragma unroll
  for (int n = 0; n < 4; ++n) {
    long col = rowB0 + wcc * 64 + n * 16 + fr;
    vw[n] = Vw[col];
#pragma unroll
    for (int h = 0; h < 2; ++h) {
      long b = (rowA0 >> 6) + wr * 2 + h;
      t2v[h][n] = t2[b * HH + col];
    }
  }
#pragma unroll
  for (int i = 0; i < 8; ++i) {
    int hsel = i >> 2;
    float part[4] = {0.f, 0.f, 0.f, 0.f};
#pragma unroll
    for (int n = 0; n < 4; ++n) {
#pragma unroll
      for (int r = 0; r < 4; ++r) {
        float tval = acc[i][n][r] + t2v[hsel][n];
        float th = 1.f - 2.f / (__expf(2.f * tval) + 1.f);
        part[r] += th * vw[n];
      }
    }
#pragma unroll
    for (int r = 0; r < 4; ++r) {
      float p = part[r];
      p += __shfl_xor(p, 1);
      p += __shfl_xor(p, 2);
      p += __shfl_xor(p, 4);
      p += __shfl_xor(p, 8);
      if (fr == 0)
        atomicAdd(&e[rowA0 + wr * 128 + i * 16 + fg * 4 + r], p);
    }
  }
#undef BAR
#undef WAIT6
}

// ---------------- fused softmax (S=64) + context -> bf16 ----------------
__global__ void softmax_ctx(const float* __restrict__ e,
                            const unsigned short* __restrict__ encb,
                            unsigned short* __restrict__ ctb) {
  __shared__ float als[2][64];
  const int tid = threadIdx.x;  // 256, block covers 2 batch rows
  const int bpair = blockIdx.x; // 256 blocks
  if (tid < 128) {
    int b = bpair * 2 + (tid >> 6), s = tid & 63;
    float v = e[b * 64 + s];
    float mx = v;
#pragma unroll
    for (int o = 32; o; o >>= 1) mx = fmaxf(mx, __shfl_xor(mx, o));
    float ex = __expf(v - mx);
    float sm = ex;
#pragma unroll
    for (int o = 32; o; o >>= 1) sm += __shfl_xor(sm, o);
    als[tid >> 6][s] = ex / sm;
  }
  __syncthreads();
  int bi = tid >> 7, hg = tid & 127;
  int b = bpair * 2 + bi;
  const unsigned short* er = encb + (long)b * (SS * HH) + hg * 8;
  float s[8] = {0.f, 0.f, 0.f, 0.f, 0.f, 0.f, 0.f, 0.f};
  for (int i = 0; i < 64; ++i) {
    float av = als[bi][i];
    bf16x8 v = *(const bf16x8*)(er + (long)i * HH);
#pragma unroll
    for (int j = 0; j < 8; ++j) s[j] += av * bf2f((unsigned short)v[j]);
  }
  unsigned short* dst = ctb + (long)b * HH + hg * 8;
#pragma unroll
  for (int j = 0; j < 8; ++j) dst[j] = f2bf(s[j]);
}

// ---------------- LSTM cell elementwise ----------------
__global__ void lstm_cell(const float* __restrict__ g, const float* __restrict__ bih,
                          const float* __restrict__ bhh, const float* __restrict__ cin,
                          float* __restrict__ hout, float* __restrict__ cout,
                          unsigned short* __restrict__ hb) {
  int idx = blockIdx.x * 256 + threadIdx.x;  // 512*1024
  int b = idx >> 10, h = idx & 1023;
  const float* gr = g + (long)b * 4096;
  float gi = gr[h] + bih[h] + bhh[h];
  float gf = gr[1024 + h] + bih[1024 + h] + bhh[1024 + h];
  float gg = gr[2048 + h] + bih[2048 + h] + bhh[2048 + h];
  float go = gr[3072 + h] + bih[3072 + h] + bhh[3072 + h];
  float si = 1.f / (1.f + __expf(-gi));
  float sf = 1.f / (1.f + __expf(-gf));
  float so = 1.f / (1.f + __expf(-go));
  float tg = 1.f - 2.f / (__expf(2.f * gg) + 1.f);
  float c2 = sf * cin[idx] + si * tg;
  float tc = 1.f - 2.f / (__expf(2.f * c2) + 1.f);
  float h2 = so * tc;
  cout[idx] = c2;
  hout[idx] = h2;
  hb[idx] = f2bf(h2);
}

extern "C" void kernel_launch(void* const* d_in, const int* in_sizes, int n_in,
                              void* d_out, int out_size, void* d_ws, size_t ws_size,
                              hipStream_t stream) {
  const int* ids = (const int*)d_in[0];
  const float* hidden = (const float*)d_in[1];
  const float* cell = (const float*)d_in[2];
  const float* enc = (const float*)d_in[3];
  const float* emb = (const float*)d_in[4];
  const float* U = (const float*)d_in[5];
  const float* W = (const float*)d_in[6];
  const float* Vw = (const float*)d_in[7];
  const float* Wih0 = (const float*)d_in[8];
  const float* Whh0 = (const float*)d_in[9];
  const float* bih0 = (const float*)d_in[10];
  const float* bhh0 = (const float*)d_in[11];
  const float* Wih1 = (const float*)d_in[12];
  const float* Whh1 = (const float*)d_in[13];
  const float* bih1 = (const float*)d_in[14];
  const float* bhh1 = (const float*)d_in[15];
  const float* out_w = (const float*)d_in[16];
  const float* out_b = (const float*)d_in[17];
  float* out = (float*)d_out;
  char* ws = (char*)d_ws;
  (void)in_sizes; (void)n_in; (void)out_size; (void)ws_size;

  unsigned short* enc_b  = (unsigned short*)(ws + OFF_ENC);
  unsigned short* Wih0b  = (unsigned short*)(ws + OFF_WIH0);
  unsigned short* Whh0b  = (unsigned short*)(ws + OFF_WHH0);
  unsigned short* Wih1b  = (unsigned short*)(ws + OFF_WIH1);
  unsigned short* Whh1b  = (unsigned short*)(ws + OFF_WHH1);
  unsigned short* outwb  = (unsigned short*)(ws + OFF_OUTW);
  unsigned short* hid0b  = (unsigned short*)(ws + OFF_HID0);
  unsigned short* hlastb = (unsigned short*)(ws + OFF_HLAST);
  unsigned short* Utb    = (unsigned short*)(ws + OFF_UT);
  unsigned short* Wtb    = (unsigned short*)(ws + OFF_WT);
  float*          t2     = (float*)(ws + OFF_T2);
  float*          e      = (float*)(ws + OFF_E);
  unsigned short* embb   = (unsigned short*)(ws + OFF_EMB);
  unsigned short* ctb    = (unsigned short*)(ws + OFF_CT);
  float*          g      = (float*)(ws + OFF_G);
  unsigned short* h0b    = (unsigned short*)(ws + OFF_H0B);
  unsigned short* h1b    = (unsigned short*)(ws + OFF_H1B);

  float* out_logits = out;
  float* h_new = out + BB * VV;
  float* c_new = h_new + 2 * BB * HH;

  // ---- prep: conversions (1 big + 2 small) ----
  cvt_all<<<2048, 256, 0, stream>>>(enc, Wih0, Whh0, Wih1, Whh1, out_w, hidden, ws);
  transpose_cvt2<<<dim3(32, 32, 2), 256, 0, stream>>>(U, W, ws);
  build_xemb<<<128, 256, 0, stream>>>(ids, emb, embb);
  hipMemsetAsync(e, 0, (size_t)BB * SS * 4, stream);

  // ---- t2 = hidden[1] @ W ----
  gemm_seg<<<dim3(4, 16), 256, 0, stream>>>(hlastb, 1024, nullptr, 0, nullptr,
                                            Wtb, 1024, nullptr, t2, HH, 1024);

  // ---- scores e (256^2 8-phase fused GEMM, reg-prefetch, XCD swizzle) ----
  (void)hipFuncSetAttribute(reinterpret_cast<const void*>(gemm_score256),
                            hipFuncAttributeMaxDynamicSharedMemorySize, 131072);
  gemm_score256<<<dim3(4, 128), 512, 131072, stream>>>(enc_b, Utb, t2, Vw, e);

  // ---- fused softmax + context ----
  softmax_ctx<<<256, 256, 0, stream>>>(e, enc_b, ctb);

  // ---- LSTM layer 0: g = [emb | ct | hid0] @ [Wih0 | Whh0]^T ----
  gemm_seg<<<dim3(4, 64), 256, 0, stream>>>(embb, 256, ctb, 1024, hid0b,
                                            Wih0b, 1280, Whh0b, g, 4 * HH, 2304);
  lstm_cell<<<BB * HH / 256, 256, 0, stream>>>(g, bih0, bhh0, cell, h_new, c_new, h0b);

  // ---- LSTM layer 1: g = [h0 | hid1] @ [Wih1 | Whh1]^T ----
  gemm_seg<<<dim3(4, 64), 256, 0, stream>>>(h0b, 1024, hlastb, 1024, nullptr,
                                            Wih1b, 1024, Whh1b, g, 4 * HH, 2048);
  lstm_cell<<<BB * HH / 256, 256, 0, stream>>>(g, bih1, bhh1, cell + BB * HH,
                                               h_new + BB * HH, c_new + BB * HH, h1b);

  // ---- output projection (split-K + bias init) ----
  init_out_bias<<<BB * VV / 256, 256, 0, stream>>>(out_b, out_logits);
  gemm_outproj<<<dim3(4, 8), 256, 0, stream>>>(h1b, outwb, out_logits);
}

// Round 4
// 237.536 us; speedup vs baseline: 1.6487x; 1.0816x over previous
//
#include <hip/hip_runtime.h>
#include <stdint.h>

// dims
#define BB 512
#define SS 64
#define HH 1024
#define EE 256
#define VV 128

typedef __attribute__((ext_vector_type(8))) short bf16x8;
typedef __attribute__((ext_vector_type(4))) float f32x4;
typedef __attribute__((ext_vector_type(8))) unsigned short u16x8;

// ---- workspace layout (bytes, all 256-aligned) ----
constexpr size_t OFF_ENC   = 0;                           // 32768x1024 bf16 = 64MB (reused as gate partial-1 after softmax_ctx)
constexpr size_t OFF_WIH0  = OFF_ENC   + 67108864UL;      // 4096x1280 bf16
constexpr size_t OFF_WHH0  = OFF_WIH0  + 10485760UL;      // 4096x1024 bf16
constexpr size_t OFF_WIH1  = OFF_WHH0  + 8388608UL;       // 4096x1024 bf16
constexpr size_t OFF_WHH1  = OFF_WIH1  + 8388608UL;       // 4096x1024 bf16
constexpr size_t OFF_OUTW  = OFF_WHH1  + 8388608UL;       // 128x1024 bf16
constexpr size_t OFF_HID0  = OFF_OUTW  + 262144UL;        // 512x1024 bf16 (input hidden[0])
constexpr size_t OFF_HLAST = OFF_HID0  + 1048576UL;       // 512x1024 bf16 (input hidden[1])
constexpr size_t OFF_UT    = OFF_HLAST + 1048576UL;       // 1024x1024 bf16 (U^T)
constexpr size_t OFF_WT    = OFF_UT    + 2097152UL;       // 1024x1024 bf16 (W^T)
constexpr size_t OFF_T2    = OFF_WT    + 2097152UL;       // 512x1024 f32
constexpr size_t OFF_E     = OFF_T2    + 2097152UL;       // 512x64 f32
constexpr size_t OFF_EMB   = OFF_E     + 131072UL;        // 512x256 bf16
constexpr size_t OFF_CT    = OFF_EMB   + 262144UL;        // 512x1024 bf16
constexpr size_t OFF_G     = OFF_CT    + 1048576UL;       // 512x4096 f32 (gate partial-0)
constexpr size_t OFF_H0B   = OFF_G     + 8388608UL;       // 512x1024 bf16 (lstm0 out)
constexpr size_t OFF_H1B   = OFF_H0B   + 1048576UL;       // 512x1024 bf16 (lstm1 out)

__device__ __forceinline__ unsigned short f2bf(float f) {
  unsigned int u = __float_as_uint(f);
  unsigned int r = (u + 0x7FFFu + ((u >> 16) & 1u)) >> 16;
  return (unsigned short)r;
}
__device__ __forceinline__ float bf2f(unsigned short h) {
  return __uint_as_float(((unsigned int)h) << 16);
}

__device__ __forceinline__ void gload_lds16(const void* g, void* l) {
  __builtin_amdgcn_global_load_lds(
      (const __attribute__((address_space(1))) unsigned int*)g,
      (__attribute__((address_space(3))) unsigned int*)l, 16, 0, 0);
}

// ---------------- high-MLP f32->bf16 conversion ----------------
// unit = 8 floats (32B src -> 16B dst). Segment bounds in units (cumulative):
constexpr long CU0 = 4194304;            // enc
constexpr long CU1 = CU0 + 655360;       // wih0
constexpr long CU2 = CU1 + 524288;       // whh0
constexpr long CU3 = CU2 + 524288;       // wih1
constexpr long CU4 = CU3 + 524288;       // whh1
constexpr long CU5 = CU4 + 16384;        // outw
constexpr long CU6 = CU5 + 65536;        // hid0
constexpr long CU7 = CU6 + 65536;        // hlast (total 6569984)

__global__ void cvt_fast(const float* __restrict__ enc, const float* __restrict__ Wih0,
                         const float* __restrict__ Whh0, const float* __restrict__ Wih1,
                         const float* __restrict__ Whh1, const float* __restrict__ outw,
                         const float* __restrict__ hid, char* __restrict__ ws) {
  auto resolve = [&](long u, const float4*& s, u16x8*& d) {
    long j;
    if (u < CU0)      { j = u;       s = (const float4*)enc  + 2 * j; d = (u16x8*)(ws + OFF_ENC)   + j; }
    else if (u < CU1) { j = u - CU0; s = (const float4*)Wih0 + 2 * j; d = (u16x8*)(ws + OFF_WIH0)  + j; }
    else if (u < CU2) { j = u - CU1; s = (const float4*)Whh0 + 2 * j; d = (u16x8*)(ws + OFF_WHH0)  + j; }
    else if (u < CU3) { j = u - CU2; s = (const float4*)Wih1 + 2 * j; d = (u16x8*)(ws + OFF_WIH1)  + j; }
    else if (u < CU4) { j = u - CU3; s = (const float4*)Whh1 + 2 * j; d = (u16x8*)(ws + OFF_WHH1)  + j; }
    else if (u < CU5) { j = u - CU4; s = (const float4*)outw + 2 * j; d = (u16x8*)(ws + OFF_OUTW)  + j; }
    else if (u < CU6) { j = u - CU5; s = (const float4*)hid  + 2 * j; d = (u16x8*)(ws + OFF_HID0)  + j; }
    else              { j = u - CU6; s = (const float4*)(hid + 524288) + 2 * j; d = (u16x8*)(ws + OFF_HLAST) + j; }
  };
  const long T = (long)gridDim.x * blockDim.x;
  long t = (long)blockIdx.x * blockDim.x + threadIdx.x;
  for (long base = t; base < CU7; base += 4 * T) {
    long u1 = base + T, u2 = base + 2 * T, u3 = base + 3 * T;
    bool a1 = u1 < CU7, a2 = u2 < CU7, a3 = u3 < CU7;
    const float4 *s0, *s1, *s2, *s3;
    u16x8 *d0, *d1, *d2, *d3;
    resolve(base, s0, d0);
    resolve(a1 ? u1 : base, s1, d1);
    resolve(a2 ? u2 : base, s2, d2);
    resolve(a3 ? u3 : base, s3, d3);
    // issue all 8 loads before any conversion (MLP)
    float4 v00 = s0[0], v01 = s0[1];
    float4 v10 = s1[0], v11 = s1[1];
    float4 v20 = s2[0], v21 = s2[1];
    float4 v30 = s3[0], v31 = s3[1];
    u16x8 o0, o1, o2, o3;
    o0[0] = f2bf(v00.x); o0[1] = f2bf(v00.y); o0[2] = f2bf(v00.z); o0[3] = f2bf(v00.w);
    o0[4] = f2bf(v01.x); o0[5] = f2bf(v01.y); o0[6] = f2bf(v01.z); o0[7] = f2bf(v01.w);
    o1[0] = f2bf(v10.x); o1[1] = f2bf(v10.y); o1[2] = f2bf(v10.z); o1[3] = f2bf(v10.w);
    o1[4] = f2bf(v11.x); o1[5] = f2bf(v11.y); o1[6] = f2bf(v11.z); o1[7] = f2bf(v11.w);
    o2[0] = f2bf(v20.x); o2[1] = f2bf(v20.y); o2[2] = f2bf(v20.z); o2[3] = f2bf(v20.w);
    o2[4] = f2bf(v21.x); o2[5] = f2bf(v21.y); o2[6] = f2bf(v21.z); o2[7] = f2bf(v21.w);
    o3[0] = f2bf(v30.x); o3[1] = f2bf(v30.y); o3[2] = f2bf(v30.z); o3[3] = f2bf(v30.w);
    o3[4] = f2bf(v31.x); o3[5] = f2bf(v31.y); o3[6] = f2bf(v31.z); o3[7] = f2bf(v31.w);
    *d0 = o0;
    if (a1) *d1 = o1;
    if (a2) *d2 = o2;
    if (a3) *d3 = o3;
  }
}

// ---------------- transpose-convert U and W (z selects) ----------------
__global__ void transpose_cvt2(const float* __restrict__ U, const float* __restrict__ W,
                               char* __restrict__ ws) {
  __shared__ float tile[32][33];
  const float* in = blockIdx.z ? W : U;
  unsigned short* out = (unsigned short*)(ws + (blockIdx.z ? OFF_WT : OFF_UT));
  int bc = blockIdx.x * 32, br = blockIdx.y * 32;
  int tx = threadIdx.x & 31, ty = threadIdx.x >> 5;
#pragma unroll
  for (int i = 0; i < 32; i += 8)
    tile[ty + i][tx] = in[(long)(br + ty + i) * HH + bc + tx];
  __syncthreads();
#pragma unroll
  for (int i = 0; i < 32; i += 8)
    out[(long)(bc + ty + i) * HH + br + tx] = f2bf(tile[tx][ty + i]);
}

// ---------------- embedded token gather -> bf16 ----------------
__global__ void build_xemb(const int* __restrict__ ids, const float* __restrict__ emb,
                           unsigned short* __restrict__ embb) {
  int t = blockIdx.x * 256 + threadIdx.x;  // 32768 = 512 * 64 float4s
  int b = t >> 6, c4 = t & 63;
  float4 v = ((const float4*)(emb + (long)ids[b] * 256))[c4];
  ushort4 o;
  o.x = f2bf(v.x); o.y = f2bf(v.y); o.z = f2bf(v.z); o.w = f2bf(v.w);
  ((ushort4*)embb)[t] = o;
}

// ---------------- segmented bf16 GEMM with split-K: C(z) = A * Bt^T over K-half z ----------------
// BM=128, BN=64, 256 threads (4 waves 2x2). A up to 3 K-segments, B up to 2.
__global__ __launch_bounds__(256) void gemm_seg(
    const unsigned short* __restrict__ A0, int KA0,
    const unsigned short* __restrict__ A1, int KA1,
    const unsigned short* __restrict__ A2,
    const unsigned short* __restrict__ B0, int KB0,
    const unsigned short* __restrict__ B1,
    float* __restrict__ C0p, float* __restrict__ C1p, int N, int Ktot, int Khalf) {
  __shared__ alignas(128) unsigned short lA[128 * 64];
  __shared__ alignas(128) unsigned short lB[64 * 64];
  const int tid = threadIdx.x;
  const int lane = tid & 63, wid = tid >> 6;
  const int wr = wid >> 1, wc = wid & 1;
  const int fr = lane & 15, fg = lane >> 4;
  f32x4 acc[4][2] = {};
  const long rowA0 = (long)blockIdx.x * 128;
  const long rowB0 = (long)blockIdx.y * 64;
  const int ktb = blockIdx.z * Khalf;
  int kte = ktb + Khalf; if (kte > Ktot) kte = Ktot;
  float* C = blockIdx.z ? C1p : C0p;
  for (int kt = ktb; kt < kte; kt += 64) {
    const unsigned short* Ap; int ka, lda;
    if (kt < KA0)            { Ap = A0; ka = kt;             lda = KA0; }
    else if (kt < KA0 + KA1) { Ap = A1; ka = kt - KA0;       lda = KA1; }
    else                     { Ap = A2; ka = kt - KA0 - KA1; lda = 1024; }
    const unsigned short* Bp; int kb, ldb;
    if (kt < KB0) { Bp = B0; kb = kt;       ldb = KB0; }
    else          { Bp = B1; kb = kt - KB0; ldb = 1024; }
#pragma unroll
    for (int j = 0; j < 4; ++j) {
      int c = j * 256 + tid;
      int r = c >> 3, cc = c & 7;
      int sc = cc ^ ((r >> 1) & 7);
      gload_lds16(Ap + (rowA0 + r) * (long)lda + ka + sc * 8, &lA[c * 8]);
    }
#pragma unroll
    for (int j = 0; j < 2; ++j) {
      int c = j * 256 + tid;
      int r = c >> 3, cc = c & 7;
      int sc = cc ^ ((r >> 1) & 7);
      gload_lds16(Bp + (rowB0 + r) * (long)ldb + kb + sc * 8, &lB[c * 8]);
    }
    __syncthreads();
#pragma unroll
    for (int kk = 0; kk < 64; kk += 32) {
      bf16x8 af[4], bfv[2];
#pragma unroll
      for (int m = 0; m < 4; ++m) {
        int row = wr * 64 + m * 16 + fr;
        int ch = ((kk >> 3) + fg) ^ ((row >> 1) & 7);
        af[m] = *(const bf16x8*)&lA[row * 64 + ch * 8];
      }
#pragma unroll
      for (int n = 0; n < 2; ++n) {
        int row = wc * 32 + n * 16 + fr;
        int ch = ((kk >> 3) + fg) ^ ((row >> 1) & 7);
        bfv[n] = *(const bf16x8*)&lB[row * 64 + ch * 8];
      }
#pragma unroll
      for (int m = 0; m < 4; ++m)
#pragma unroll
        for (int n = 0; n < 2; ++n)
          acc[m][n] = __builtin_amdgcn_mfma_f32_16x16x32_bf16(af[m], bfv[n],
                                                              acc[m][n], 0, 0, 0);
    }
    __syncthreads();
  }
#pragma unroll
  for (int m = 0; m < 4; ++m)
#pragma unroll
    for (int n = 0; n < 2; ++n)
#pragma unroll
      for (int r = 0; r < 4; ++r) {
        long grow = rowA0 + wr * 64 + m * 16 + fg * 4 + r;
        long gcol = rowB0 + wc * 32 + n * 16 + fr;
        C[grow * N + gcol] = acc[m][n][r];
      }
}

// ---------------- out projection, split-K, atomic accumulate ----------------
__global__ __launch_bounds__(256) void gemm_outproj(
    const unsigned short* __restrict__ A, const unsigned short* __restrict__ Bt,
    float* __restrict__ C) {
  __shared__ alignas(128) unsigned short lA[128 * 64];
  __shared__ alignas(128) unsigned short lB[128 * 64];
  const int tid = threadIdx.x;
  const int lane = tid & 63, wid = tid >> 6;
  const int wr = wid >> 1, wc = wid & 1;
  const int fr = lane & 15, fg = lane >> 4;
  f32x4 acc[4][4] = {};
  const long rowA0 = (long)blockIdx.x * 128;
  const int k0 = blockIdx.y * 128;
  for (int kt = k0; kt < k0 + 128; kt += 64) {
#pragma unroll
    for (int j = 0; j < 4; ++j) {
      int c = j * 256 + tid;
      int r = c >> 3, cc = c & 7;
      gload_lds16(A + (rowA0 + r) * 1024 + kt + cc * 8, &lA[c * 8]);
    }
#pragma unroll
    for (int j = 0; j < 4; ++j) {
      int c = j * 256 + tid;
      int r = c >> 3, cc = c & 7;
      gload_lds16(Bt + (long)r * 1024 + kt + cc * 8, &lB[c * 8]);
    }
    __syncthreads();
#pragma unroll
    for (int kk = 0; kk < 64; kk += 32) {
      bf16x8 af[4], bfv[4];
#pragma unroll
      for (int m = 0; m < 4; ++m)
        af[m] = *(const bf16x8*)&lA[(wr * 64 + m * 16 + fr) * 64 + kk + fg * 8];
#pragma unroll
      for (int n = 0; n < 4; ++n)
        bfv[n] = *(const bf16x8*)&lB[(wc * 64 + n * 16 + fr) * 64 + kk + fg * 8];
#pragma unroll
      for (int m = 0; m < 4; ++m)
#pragma unroll
        for (int n = 0; n < 4; ++n)
          acc[m][n] = __builtin_amdgcn_mfma_f32_16x16x32_bf16(af[m], bfv[n],
                                                              acc[m][n], 0, 0, 0);
    }
    __syncthreads();
  }
#pragma unroll
  for (int m = 0; m < 4; ++m)
#pragma unroll
    for (int n = 0; n < 4; ++n)
#pragma unroll
      for (int r = 0; r < 4; ++r) {
        long grow = rowA0 + wr * 64 + m * 16 + fg * 4 + r;
        long gcol = wc * 64 + n * 16 + fr;
        atomicAdd(&C[grow * 128 + gcol], acc[m][n][r]);
      }
}

__global__ void init_out_bias(const float* __restrict__ ob, float* __restrict__ out) {
  int i = blockIdx.x * 256 + threadIdx.x;
  out[i] = ob[i & 127];
}

// ---------------- 256x256 8-phase score GEMM with reg-prefetch + XCD swizzle ----------------
__global__ __launch_bounds__(512, 2) void gemm_score256(
    const unsigned short* __restrict__ A, const unsigned short* __restrict__ Bt,
    const float* __restrict__ t2, const float* __restrict__ Vw,
    float* __restrict__ e) {
  extern __shared__ unsigned short smem[];  // [2][4][8192]
  const int K = HH;
  const int tid = threadIdx.x;
  const int lane = tid & 63, wid = tid >> 6;
  const int wr = wid >> 2;       // M half (128 rows)
  const int wcc = wid & 3;       // N quarter (64 cols)
  const int fr = lane & 15, fg = lane >> 4;
  int flat = blockIdx.y * 4 + blockIdx.x;
  int swz = (flat & 7) * 64 + (flat >> 3);
  const long rowA0 = (long)(swz >> 2) * 256;
  const long rowB0 = (long)(swz & 3) * 256;
  const int NKT = 16, NIT = 8;

  f32x4 acc[8][4] = {};

  auto RA = [&](int buf, int kh) { return (const unsigned short*)(smem + (buf * 4 + kh * 2) * 8192); };
  auto RB = [&](int buf, int kh) { return (const unsigned short*)(smem + (buf * 4 + kh * 2 + 1) * 8192); };

  auto stage = [&](int buf, int reg, int ktile) {
    const unsigned short* base = (reg & 1) ? Bt : A;
    long r0 = (reg & 1) ? rowB0 : rowA0;
    int kb = ktile * 64 + (reg >> 1) * 32;
    unsigned short* dst = smem + (buf * 4 + reg) * 8192;
#pragma unroll
    for (int j = 0; j < 2; ++j) {
      int c = j * 512 + tid;
      int row = c >> 2;
      int fgl = (c & 3) ^ ((row >> 1) & 3);
      gload_lds16(base + (r0 + row) * (long)K + kb + fgl * 8, dst + c * 8);
    }
  };
  auto readA = [&](const unsigned short* rg, int mh, bf16x8* af) {
#pragma unroll
    for (int m = 0; m < 4; ++m) {
      int row = wr * 128 + mh * 64 + m * 16 + fr;
      int slot = fg ^ ((row >> 1) & 3);
      af[m] = *(const bf16x8*)(rg + row * 32 + slot * 8);
    }
  };
  auto readB = [&](const unsigned short* rg, bf16x8* bv) {
#pragma unroll
    for (int n = 0; n < 4; ++n) {
      int row = wcc * 64 + n * 16 + fr;
      int slot = fg ^ ((row >> 1) & 3);
      bv[n] = *(const bf16x8*)(rg + row * 32 + slot * 8);
    }
  };
  auto mfma16 = [&](int mh, const bf16x8* af, const bf16x8* bv) {
    __builtin_amdgcn_s_setprio(1);
#pragma unroll
    for (int m = 0; m < 4; ++m)
#pragma unroll
      for (int n = 0; n < 4; ++n)
        acc[mh * 4 + m][n] = __builtin_amdgcn_mfma_f32_16x16x32_bf16(
            af[m], bv[n], acc[mh * 4 + m][n], 0, 0, 0);
    __builtin_amdgcn_s_setprio(0);
  };

#define BAR() __builtin_amdgcn_s_barrier()
#define WAIT6() asm volatile("s_waitcnt vmcnt(6)" ::: "memory")

  bf16x8 afA[4], afB[4], bvA[4], bvB[4];

  stage(0, 0, 0); stage(0, 1, 0); stage(0, 2, 0); stage(0, 3, 0);
  stage(1, 0, 1); stage(1, 1, 1);
  asm volatile("s_waitcnt vmcnt(8)" ::: "memory");
  BAR();
  readA(RA(0, 0), 0, afA); readB(RB(0, 0), bvA);

  for (int t = 0; t < NIT; ++t) {
    int k1 = 2 * t + 1, k2 = 2 * t + 2, k3 = 2 * t + 3;
    if (k2 >= NKT) k2 -= NKT;
    if (k3 >= NKT) k3 -= NKT;
    // p1
    readA(RA(0, 0), 1, afB);
    stage(1, 2, k1);
    BAR(); mfma16(0, afA, bvA); BAR();
    // p2
    WAIT6();
    readA(RA(0, 1), 0, afA); readB(RB(0, 1), bvB);
    stage(1, 3, k1);
    BAR(); mfma16(1, afB, bvA); BAR();
    // p3
    readA(RA(0, 1), 1, afB);
    stage(0, 0, k2);
    BAR(); mfma16(0, afA, bvB); BAR();
    // p4
    WAIT6();
    readA(RA(1, 0), 0, afA); readB(RB(1, 0), bvA);
    stage(0, 1, k2);
    BAR(); mfma16(1, afB, bvB); BAR();
    // p5
    readA(RA(1, 0), 1, afB);
    stage(0, 2, k2);
    BAR(); mfma16(0, afA, bvA); BAR();
    // p6
    WAIT6();
    readA(RA(1, 1), 0, afA); readB(RB(1, 1), bvB);
    stage(0, 3, k2);
    BAR(); mfma16(1, afB, bvA); BAR();
    // p7
    readA(RA(1, 1), 1, afB);
    stage(1, 0, k3);
    BAR(); mfma16(0, afA, bvB); BAR();
    // p8
    WAIT6();
    readA(RA(0, 0), 0, afA); readB(RB(0, 0), bvA);
    stage(1, 1, k3);
    BAR(); mfma16(1, afB, bvB); BAR();
  }
  asm volatile("s_waitcnt vmcnt(0)" ::: "memory");

  float t2v[2][4], vw[4];
#pragma unroll
  for (int n = 0; n < 4; ++n) {
    long col = rowB0 + wcc * 64 + n * 16 + fr;
    vw[n] = Vw[col];
#pragma unroll
    for (int h = 0; h < 2; ++h) {
      long b = (rowA0 >> 6) + wr * 2 + h;
      t2v[h][n] = t2[b * HH + col];
    }
  }
#pragma unroll
  for (int i = 0; i < 8; ++i) {
    int hsel = i >> 2;
    float part[4] = {0.f, 0.f, 0.f, 0.f};
#pragma unroll
    for (int n = 0; n < 4; ++n) {
#pragma unroll
      for (int r = 0; r < 4; ++r) {
        float tval = acc[i][n][r] + t2v[hsel][n];
        float th = 1.f - 2.f / (__expf(2.f * tval) + 1.f);
        part[r] += th * vw[n];
      }
    }
#pragma unroll
    for (int r = 0; r < 4; ++r) {
      float p = part[r];
      p += __shfl_xor(p, 1);
      p += __shfl_xor(p, 2);
      p += __shfl_xor(p, 4);
      p += __shfl_xor(p, 8);
      if (fr == 0)
        atomicAdd(&e[rowA0 + wr * 128 + i * 16 + fg * 4 + r], p);
    }
  }
#undef BAR
#undef WAIT6
}

// ---------------- fused softmax (S=64) + context -> bf16 ----------------
__global__ void softmax_ctx(const float* __restrict__ e,
                            const unsigned short* __restrict__ encb,
                            unsigned short* __restrict__ ctb) {
  __shared__ float als[2][64];
  const int tid = threadIdx.x;
  const int bpair = blockIdx.x;
  if (tid < 128) {
    int b = bpair * 2 + (tid >> 6), s = tid & 63;
    float v = e[b * 64 + s];
    float mx = v;
#pragma unroll
    for (int o = 32; o; o >>= 1) mx = fmaxf(mx, __shfl_xor(mx, o));
    float ex = __expf(v - mx);
    float sm = ex;
#pragma unroll
    for (int o = 32; o; o >>= 1) sm += __shfl_xor(sm, o);
    als[tid >> 6][s] = ex / sm;
  }
  __syncthreads();
  int bi = tid >> 7, hg = tid & 127;
  int b = bpair * 2 + bi;
  const unsigned short* er = encb + (long)b * (SS * HH) + hg * 8;
  float s[8] = {0.f, 0.f, 0.f, 0.f, 0.f, 0.f, 0.f, 0.f};
  for (int i = 0; i < 64; ++i) {
    float av = als[bi][i];
    bf16x8 v = *(const bf16x8*)(er + (long)i * HH);
#pragma unroll
    for (int j = 0; j < 8; ++j) s[j] += av * bf2f((unsigned short)v[j]);
  }
  unsigned short* dst = ctb + (long)b * HH + hg * 8;
#pragma unroll
  for (int j = 0; j < 8; ++j) dst[j] = f2bf(s[j]);
}

// ---------------- LSTM cell elementwise (sums two split-K partials) ----------------
__global__ void lstm_cell(const float* __restrict__ g0, const float* __restrict__ g1,
                          const float* __restrict__ bih, const float* __restrict__ bhh,
                          const float* __restrict__ cin,
                          float* __restrict__ hout, float* __restrict__ cout,
                          unsigned short* __restrict__ hb) {
  int idx = blockIdx.x * 256 + threadIdx.x;  // 512*1024
  int b = idx >> 10, h = idx & 1023;
  const float* gr0 = g0 + (long)b * 4096;
  const float* gr1 = g1 + (long)b * 4096;
  float gi = gr0[h] + gr1[h] + bih[h] + bhh[h];
  float gf = gr0[1024 + h] + gr1[1024 + h] + bih[1024 + h] + bhh[1024 + h];
  float gg = gr0[2048 + h] + gr1[2048 + h] + bih[2048 + h] + bhh[2048 + h];
  float go = gr0[3072 + h] + gr1[3072 + h] + bih[3072 + h] + bhh[3072 + h];
  float si = 1.f / (1.f + __expf(-gi));
  float sf = 1.f / (1.f + __expf(-gf));
  float so = 1.f / (1.f + __expf(-go));
  float tg = 1.f - 2.f / (__expf(2.f * gg) + 1.f);
  float c2 = sf * cin[idx] + si * tg;
  float tc = 1.f - 2.f / (__expf(2.f * c2) + 1.f);
  float h2 = so * tc;
  cout[idx] = c2;
  hout[idx] = h2;
  hb[idx] = f2bf(h2);
}

extern "C" void kernel_launch(void* const* d_in, const int* in_sizes, int n_in,
                              void* d_out, int out_size, void* d_ws, size_t ws_size,
                              hipStream_t stream) {
  const int* ids = (const int*)d_in[0];
  const float* hidden = (const float*)d_in[1];
  const float* cell = (const float*)d_in[2];
  const float* enc = (const float*)d_in[3];
  const float* emb = (const float*)d_in[4];
  const float* U = (const float*)d_in[5];
  const float* W = (const float*)d_in[6];
  const float* Vw = (const float*)d_in[7];
  const float* Wih0 = (const float*)d_in[8];
  const float* Whh0 = (const float*)d_in[9];
  const float* bih0 = (const float*)d_in[10];
  const float* bhh0 = (const float*)d_in[11];
  const float* Wih1 = (const float*)d_in[12];
  const float* Whh1 = (const float*)d_in[13];
  const float* bih1 = (const float*)d_in[14];
  const float* bhh1 = (const float*)d_in[15];
  const float* out_w = (const float*)d_in[16];
  const float* out_b = (const float*)d_in[17];
  float* out = (float*)d_out;
  char* ws = (char*)d_ws;
  (void)in_sizes; (void)n_in; (void)out_size; (void)ws_size;

  unsigned short* enc_b  = (unsigned short*)(ws + OFF_ENC);
  unsigned short* Wih0b  = (unsigned short*)(ws + OFF_WIH0);
  unsigned short* Whh0b  = (unsigned short*)(ws + OFF_WHH0);
  unsigned short* Wih1b  = (unsigned short*)(ws + OFF_WIH1);
  unsigned short* Whh1b  = (unsigned short*)(ws + OFF_WHH1);
  unsigned short* outwb  = (unsigned short*)(ws + OFF_OUTW);
  unsigned short* hid0b  = (unsigned short*)(ws + OFF_HID0);
  unsigned short* hlastb = (unsigned short*)(ws + OFF_HLAST);
  unsigned short* Utb    = (unsigned short*)(ws + OFF_UT);
  unsigned short* Wtb    = (unsigned short*)(ws + OFF_WT);
  float*          t2     = (float*)(ws + OFF_T2);
  float*          e      = (float*)(ws + OFF_E);
  unsigned short* embb   = (unsigned short*)(ws + OFF_EMB);
  unsigned short* ctb    = (unsigned short*)(ws + OFF_CT);
  float*          g      = (float*)(ws + OFF_G);
  float*          gB     = (float*)(ws + OFF_ENC);  // gate partial-1: aliases enc_b (dead after softmax_ctx)
  unsigned short* h0b    = (unsigned short*)(ws + OFF_H0B);
  unsigned short* h1b    = (unsigned short*)(ws + OFF_H1B);

  float* out_logits = out;
  float* h_new = out + BB * VV;
  float* c_new = h_new + 2 * BB * HH;

  // ---- prep: conversions ----
  cvt_fast<<<2048, 256, 0, stream>>>(enc, Wih0, Whh0, Wih1, Whh1, out_w, hidden, ws);
  transpose_cvt2<<<dim3(32, 32, 2), 256, 0, stream>>>(U, W, ws);
  build_xemb<<<128, 256, 0, stream>>>(ids, emb, embb);
  hipMemsetAsync(e, 0, (size_t)BB * SS * 4, stream);

  // ---- t2 = hidden[1] @ W ----
  gemm_seg<<<dim3(4, 16, 1), 256, 0, stream>>>(hlastb, 1024, nullptr, 0, nullptr,
                                               Wtb, 1024, nullptr, t2, t2, HH, 1024, 1024);

  // ---- scores e (256^2 8-phase fused GEMM) ----
  (void)hipFuncSetAttribute(reinterpret_cast<const void*>(gemm_score256),
                            hipFuncAttributeMaxDynamicSharedMemorySize, 131072);
  gemm_score256<<<dim3(4, 128), 512, 131072, stream>>>(enc_b, Utb, t2, Vw, e);

  // ---- fused softmax + context ----
  softmax_ctx<<<256, 256, 0, stream>>>(e, enc_b, ctb);

  // ---- LSTM layer 0: g = [emb | ct | hid0] @ [Wih0 | Whh0]^T, split-K 1152/1152 ----
  gemm_seg<<<dim3(4, 64, 2), 256, 0, stream>>>(embb, 256, ctb, 1024, hid0b,
                                               Wih0b, 1280, Whh0b, g, gB, 4 * HH, 2304, 1152);
  lstm_cell<<<BB * HH / 256, 256, 0, stream>>>(g, gB, bih0, bhh0, cell, h_new, c_new, h0b);

  // ---- LSTM layer 1: g = [h0 | hid1] @ [Wih1 | Whh1]^T, split-K 1024/1024 ----
  gemm_seg<<<dim3(4, 64, 2), 256, 0, stream>>>(h0b, 1024, hlastb, 1024, nullptr,
                                               Wih1b, 1024, Whh1b, g, gB, 4 * HH, 2048, 1024);
  lstm_cell<<<BB * HH / 256, 256, 0, stream>>>(g, gB, bih1, bhh1, cell + BB * HH,
                                               h_new + BB * HH, c_new + BB * HH, h1b);

  // ---- output projection (split-K + bias init) ----
  init_out_bias<<<BB * VV / 256, 256, 0, stream>>>(out_b, out_logits);
  gemm_outproj<<<dim3(4, 8), 256, 0, stream>>>(h1b, outwb, out_logits);
}

// Round 5
// 226.637 us; speedup vs baseline: 1.7280x; 1.0481x over previous
//
#include <hip/hip_runtime.h>
#include <stdint.h>

// dims
#define BB 512
#define SS 64
#define HH 1024
#define EE 256
#define VV 128

typedef __attribute__((ext_vector_type(8))) short bf16x8;
typedef __attribute__((ext_vector_type(4))) float f32x4;
typedef __attribute__((ext_vector_type(8))) unsigned short u16x8;

// ---- workspace layout (bytes, all 256-aligned) ----
constexpr size_t OFF_ENC   = 0;                           // 32768x1024 bf16 = 64MB (reused as gate partial-1 after softmax_ctx)
constexpr size_t OFF_WIH0  = OFF_ENC   + 67108864UL;      // 4096x1280 bf16
constexpr size_t OFF_WHH0  = OFF_WIH0  + 10485760UL;      // 4096x1024 bf16
constexpr size_t OFF_WIH1  = OFF_WHH0  + 8388608UL;       // 4096x1024 bf16
constexpr size_t OFF_WHH1  = OFF_WIH1  + 8388608UL;       // 4096x1024 bf16
constexpr size_t OFF_OUTW  = OFF_WHH1  + 8388608UL;       // 128x1024 bf16
constexpr size_t OFF_HID0  = OFF_OUTW  + 262144UL;        // 512x1024 bf16 (input hidden[0])
constexpr size_t OFF_HLAST = OFF_HID0  + 1048576UL;       // 512x1024 bf16 (input hidden[1])
constexpr size_t OFF_UT    = OFF_HLAST + 1048576UL;       // 1024x1024 bf16 (U^T)
constexpr size_t OFF_WT    = OFF_UT    + 2097152UL;       // 1024x1024 bf16 (W^T)
constexpr size_t OFF_T2    = OFF_WT    + 2097152UL;       // 512x1024 f32
constexpr size_t OFF_E     = OFF_T2    + 2097152UL;       // 512x64 f32
constexpr size_t OFF_EMB   = OFF_E     + 131072UL;        // 512x256 bf16
constexpr size_t OFF_CT    = OFF_EMB   + 262144UL;        // 512x1024 bf16
constexpr size_t OFF_G     = OFF_CT    + 1048576UL;       // 512x4096 f32 (gate partial-0)
constexpr size_t OFF_H0B   = OFF_G     + 8388608UL;       // 512x1024 bf16 (lstm0 out)
constexpr size_t OFF_H1B   = OFF_H0B   + 1048576UL;       // 512x1024 bf16 (lstm1 out)

__device__ __forceinline__ unsigned short f2bf(float f) {
  unsigned int u = __float_as_uint(f);
  unsigned int r = (u + 0x7FFFu + ((u >> 16) & 1u)) >> 16;
  return (unsigned short)r;
}
__device__ __forceinline__ float bf2f(unsigned short h) {
  return __uint_as_float(((unsigned int)h) << 16);
}

__device__ __forceinline__ void gload_lds16(const void* g, void* l) {
  __builtin_amdgcn_global_load_lds(
      (const __attribute__((address_space(1))) unsigned int*)g,
      (__attribute__((address_space(3))) unsigned int*)l, 16, 0, 0);
}

// ---------------- f32->bf16 conversion, block-uniform segments ----------------
// unit = 8 floats (32B src -> 16B dst). Each block converts 1024 units; every
// segment boundary is a multiple of 1024 units, so segment resolve is a
// block-uniform scalar branch and the hot path is straight-line (8 loads
// batched in one basic block -> full MLP).
constexpr long CU0 = 4194304;            // enc
constexpr long CU1 = CU0 + 655360;       // wih0
constexpr long CU2 = CU1 + 524288;       // whh0
constexpr long CU3 = CU2 + 524288;       // wih1
constexpr long CU4 = CU3 + 524288;       // whh1
constexpr long CU5 = CU4 + 16384;        // outw
constexpr long CU6 = CU5 + 65536;        // hid0
constexpr long CU7 = CU6 + 65536;        // hlast (total 6569984 units = 6416 blocks)

__global__ __launch_bounds__(256) void cvt_fast(
    const float* __restrict__ enc, const float* __restrict__ Wih0,
    const float* __restrict__ Whh0, const float* __restrict__ Wih1,
    const float* __restrict__ Whh1, const float* __restrict__ outw,
    const float* __restrict__ hid, char* __restrict__ ws) {
  const long ub = (long)blockIdx.x << 10;
  const float* __restrict__ src;
  char* dstb;
  long s0;
  if (ub < CU0)      { src = enc;          dstb = ws + OFF_ENC;   s0 = 0; }
  else if (ub < CU1) { src = Wih0;         dstb = ws + OFF_WIH0;  s0 = CU0; }
  else if (ub < CU2) { src = Whh0;         dstb = ws + OFF_WHH0;  s0 = CU1; }
  else if (ub < CU3) { src = Wih1;         dstb = ws + OFF_WIH1;  s0 = CU2; }
  else if (ub < CU4) { src = Whh1;         dstb = ws + OFF_WHH1;  s0 = CU3; }
  else if (ub < CU5) { src = outw;         dstb = ws + OFF_OUTW;  s0 = CU4; }
  else if (ub < CU6) { src = hid;          dstb = ws + OFF_HID0;  s0 = CU5; }
  else               { src = hid + 524288; dstb = ws + OFF_HLAST; s0 = CU6; }
  const long r = ub - s0 + threadIdx.x;
  const float4* __restrict__ sp = (const float4*)src;
  u16x8* __restrict__ dp = (u16x8*)dstb;
  // 8 independent loads, one basic block
  float4 va0 = sp[2 * r + 0],          vb0 = sp[2 * r + 1];
  float4 va1 = sp[2 * (r + 256) + 0],  vb1 = sp[2 * (r + 256) + 1];
  float4 va2 = sp[2 * (r + 512) + 0],  vb2 = sp[2 * (r + 512) + 1];
  float4 va3 = sp[2 * (r + 768) + 0],  vb3 = sp[2 * (r + 768) + 1];
  u16x8 o0, o1, o2, o3;
  o0[0] = f2bf(va0.x); o0[1] = f2bf(va0.y); o0[2] = f2bf(va0.z); o0[3] = f2bf(va0.w);
  o0[4] = f2bf(vb0.x); o0[5] = f2bf(vb0.y); o0[6] = f2bf(vb0.z); o0[7] = f2bf(vb0.w);
  o1[0] = f2bf(va1.x); o1[1] = f2bf(va1.y); o1[2] = f2bf(va1.z); o1[3] = f2bf(va1.w);
  o1[4] = f2bf(vb1.x); o1[5] = f2bf(vb1.y); o1[6] = f2bf(vb1.z); o1[7] = f2bf(vb1.w);
  o2[0] = f2bf(va2.x); o2[1] = f2bf(va2.y); o2[2] = f2bf(va2.z); o2[3] = f2bf(va2.w);
  o2[4] = f2bf(vb2.x); o2[5] = f2bf(vb2.y); o2[6] = f2bf(vb2.z); o2[7] = f2bf(vb2.w);
  o3[0] = f2bf(va3.x); o3[1] = f2bf(va3.y); o3[2] = f2bf(va3.z); o3[3] = f2bf(va3.w);
  o3[4] = f2bf(vb3.x); o3[5] = f2bf(vb3.y); o3[6] = f2bf(vb3.z); o3[7] = f2bf(vb3.w);
  dp[r] = o0;
  dp[r + 256] = o1;
  dp[r + 512] = o2;
  dp[r + 768] = o3;
}

// ---------------- transpose-convert U and W (z selects) ----------------
__global__ void transpose_cvt2(const float* __restrict__ U, const float* __restrict__ W,
                               char* __restrict__ ws) {
  __shared__ float tile[32][33];
  const float* in = blockIdx.z ? W : U;
  unsigned short* out = (unsigned short*)(ws + (blockIdx.z ? OFF_WT : OFF_UT));
  int bc = blockIdx.x * 32, br = blockIdx.y * 32;
  int tx = threadIdx.x & 31, ty = threadIdx.x >> 5;
#pragma unroll
  for (int i = 0; i < 32; i += 8)
    tile[ty + i][tx] = in[(long)(br + ty + i) * HH + bc + tx];
  __syncthreads();
#pragma unroll
  for (int i = 0; i < 32; i += 8)
    out[(long)(bc + ty + i) * HH + br + tx] = f2bf(tile[tx][ty + i]);
}

// ---------------- embedded token gather -> bf16 ----------------
__global__ void build_xemb(const int* __restrict__ ids, const float* __restrict__ emb,
                           unsigned short* __restrict__ embb) {
  int t = blockIdx.x * 256 + threadIdx.x;  // 32768 = 512 * 64 float4s
  int b = t >> 6, c4 = t & 63;
  float4 v = ((const float4*)(emb + (long)ids[b] * 256))[c4];
  ushort4 o;
  o.x = f2bf(v.x); o.y = f2bf(v.y); o.z = f2bf(v.z); o.w = f2bf(v.w);
  ((ushort4*)embb)[t] = o;
}

// ---------------- segmented bf16 GEMM with split-K: C(z) = A * Bt^T over K-half z ----------------
// BM=128, BN=64, 256 threads (4 waves 2x2). A up to 3 K-segments, B up to 2.
__global__ __launch_bounds__(256) void gemm_seg(
    const unsigned short* __restrict__ A0, int KA0,
    const unsigned short* __restrict__ A1, int KA1,
    const unsigned short* __restrict__ A2,
    const unsigned short* __restrict__ B0, int KB0,
    const unsigned short* __restrict__ B1,
    float* __restrict__ C0p, float* __restrict__ C1p, int N, int Ktot, int Khalf) {
  __shared__ alignas(128) unsigned short lA[128 * 64];
  __shared__ alignas(128) unsigned short lB[64 * 64];
  const int tid = threadIdx.x;
  const int lane = tid & 63, wid = tid >> 6;
  const int wr = wid >> 1, wc = wid & 1;
  const int fr = lane & 15, fg = lane >> 4;
  f32x4 acc[4][2] = {};
  const long rowA0 = (long)blockIdx.x * 128;
  const long rowB0 = (long)blockIdx.y * 64;
  const int ktb = blockIdx.z * Khalf;
  int kte = ktb + Khalf; if (kte > Ktot) kte = Ktot;
  float* C = blockIdx.z ? C1p : C0p;
  for (int kt = ktb; kt < kte; kt += 64) {
    const unsigned short* Ap; int ka, lda;
    if (kt < KA0)            { Ap = A0; ka = kt;             lda = KA0; }
    else if (kt < KA0 + KA1) { Ap = A1; ka = kt - KA0;       lda = KA1; }
    else                     { Ap = A2; ka = kt - KA0 - KA1; lda = 1024; }
    const unsigned short* Bp; int kb, ldb;
    if (kt < KB0) { Bp = B0; kb = kt;       ldb = KB0; }
    else          { Bp = B1; kb = kt - KB0; ldb = 1024; }
#pragma unroll
    for (int j = 0; j < 4; ++j) {
      int c = j * 256 + tid;
      int r = c >> 3, cc = c & 7;
      int sc = cc ^ ((r >> 1) & 7);
      gload_lds16(Ap + (rowA0 + r) * (long)lda + ka + sc * 8, &lA[c * 8]);
    }
#pragma unroll
    for (int j = 0; j < 2; ++j) {
      int c = j * 256 + tid;
      int r = c >> 3, cc = c & 7;
      int sc = cc ^ ((r >> 1) & 7);
      gload_lds16(Bp + (rowB0 + r) * (long)ldb + kb + sc * 8, &lB[c * 8]);
    }
    __syncthreads();
#pragma unroll
    for (int kk = 0; kk < 64; kk += 32) {
      bf16x8 af[4], bfv[2];
#pragma unroll
      for (int m = 0; m < 4; ++m) {
        int row = wr * 64 + m * 16 + fr;
        int ch = ((kk >> 3) + fg) ^ ((row >> 1) & 7);
        af[m] = *(const bf16x8*)&lA[row * 64 + ch * 8];
      }
#pragma unroll
      for (int n = 0; n < 2; ++n) {
        int row = wc * 32 + n * 16 + fr;
        int ch = ((kk >> 3) + fg) ^ ((row >> 1) & 7);
        bfv[n] = *(const bf16x8*)&lB[row * 64 + ch * 8];
      }
#pragma unroll
      for (int m = 0; m < 4; ++m)
#pragma unroll
        for (int n = 0; n < 2; ++n)
          acc[m][n] = __builtin_amdgcn_mfma_f32_16x16x32_bf16(af[m], bfv[n],
                                                              acc[m][n], 0, 0, 0);
    }
    __syncthreads();
  }
#pragma unroll
  for (int m = 0; m < 4; ++m)
#pragma unroll
    for (int n = 0; n < 2; ++n)
#pragma unroll
      for (int r = 0; r < 4; ++r) {
        long grow = rowA0 + wr * 64 + m * 16 + fg * 4 + r;
        long gcol = rowB0 + wc * 32 + n * 16 + fr;
        C[grow * N + gcol] = acc[m][n][r];
      }
}

// ---------------- out projection, split-K, atomic accumulate ----------------
__global__ __launch_bounds__(256) void gemm_outproj(
    const unsigned short* __restrict__ A, const unsigned short* __restrict__ Bt,
    float* __restrict__ C) {
  __shared__ alignas(128) unsigned short lA[128 * 64];
  __shared__ alignas(128) unsigned short lB[128 * 64];
  const int tid = threadIdx.x;
  const int lane = tid & 63, wid = tid >> 6;
  const int wr = wid >> 1, wc = wid & 1;
  const int fr = lane & 15, fg = lane >> 4;
  f32x4 acc[4][4] = {};
  const long rowA0 = (long)blockIdx.x * 128;
  const int k0 = blockIdx.y * 128;
  for (int kt = k0; kt < k0 + 128; kt += 64) {
#pragma unroll
    for (int j = 0; j < 4; ++j) {
      int c = j * 256 + tid;
      int r = c >> 3, cc = c & 7;
      gload_lds16(A + (rowA0 + r) * 1024 + kt + cc * 8, &lA[c * 8]);
    }
#pragma unroll
    for (int j = 0; j < 4; ++j) {
      int c = j * 256 + tid;
      int r = c >> 3, cc = c & 7;
      gload_lds16(Bt + (long)r * 1024 + kt + cc * 8, &lB[c * 8]);
    }
    __syncthreads();
#pragma unroll
    for (int kk = 0; kk < 64; kk += 32) {
      bf16x8 af[4], bfv[4];
#pragma unroll
      for (int m = 0; m < 4; ++m)
        af[m] = *(const bf16x8*)&lA[(wr * 64 + m * 16 + fr) * 64 + kk + fg * 8];
#pragma unroll
      for (int n = 0; n < 4; ++n)
        bfv[n] = *(const bf16x8*)&lB[(wc * 64 + n * 16 + fr) * 64 + kk + fg * 8];
#pragma unroll
      for (int m = 0; m < 4; ++m)
#pragma unroll
        for (int n = 0; n < 4; ++n)
          acc[m][n] = __builtin_amdgcn_mfma_f32_16x16x32_bf16(af[m], bfv[n],
                                                              acc[m][n], 0, 0, 0);
    }
    __syncthreads();
  }
#pragma unroll
  for (int m = 0; m < 4; ++m)
#pragma unroll
    for (int n = 0; n < 4; ++n)
#pragma unroll
      for (int r = 0; r < 4; ++r) {
        long grow = rowA0 + wr * 64 + m * 16 + fg * 4 + r;
        long gcol = wc * 64 + n * 16 + fr;
        atomicAdd(&C[grow * 128 + gcol], acc[m][n][r]);
      }
}

__global__ void init_out_bias(const float* __restrict__ ob, float* __restrict__ out) {
  int i = blockIdx.x * 256 + threadIdx.x;
  out[i] = ob[i & 127];
}

// ---------------- 256x256 8-phase score GEMM with reg-prefetch + XCD swizzle ----------------
__global__ __launch_bounds__(512, 2) void gemm_score256(
    const unsigned short* __restrict__ A, const unsigned short* __restrict__ Bt,
    const float* __restrict__ t2, const float* __restrict__ Vw,
    float* __restrict__ e) {
  extern __shared__ unsigned short smem[];  // [2][4][8192]
  const int K = HH;
  const int tid = threadIdx.x;
  const int lane = tid & 63, wid = tid >> 6;
  const int wr = wid >> 2;       // M half (128 rows)
  const int wcc = wid & 3;       // N quarter (64 cols)
  const int fr = lane & 15, fg = lane >> 4;
  int flat = blockIdx.y * 4 + blockIdx.x;
  int swz = (flat & 7) * 64 + (flat >> 3);
  const long rowA0 = (long)(swz >> 2) * 256;
  const long rowB0 = (long)(swz & 3) * 256;
  const int NKT = 16, NIT = 8;

  f32x4 acc[8][4] = {};

  auto RA = [&](int buf, int kh) { return (const unsigned short*)(smem + (buf * 4 + kh * 2) * 8192); };
  auto RB = [&](int buf, int kh) { return (const unsigned short*)(smem + (buf * 4 + kh * 2 + 1) * 8192); };

  auto stage = [&](int buf, int reg, int ktile) {
    const unsigned short* base = (reg & 1) ? Bt : A;
    long r0 = (reg & 1) ? rowB0 : rowA0;
    int kb = ktile * 64 + (reg >> 1) * 32;
    unsigned short* dst = smem + (buf * 4 + reg) * 8192;
#pragma unroll
    for (int j = 0; j < 2; ++j) {
      int c = j * 512 + tid;
      int row = c >> 2;
      int fgl = (c & 3) ^ ((row >> 1) & 3);
      gload_lds16(base + (r0 + row) * (long)K + kb + fgl * 8, dst + c * 8);
    }
  };
  auto readA = [&](const unsigned short* rg, int mh, bf16x8* af) {
#pragma unroll
    for (int m = 0; m < 4; ++m) {
      int row = wr * 128 + mh * 64 + m * 16 + fr;
      int slot = fg ^ ((row >> 1) & 3);
      af[m] = *(const bf16x8*)(rg + row * 32 + slot * 8);
    }
  };
  auto readB = [&](const unsigned short* rg, bf16x8* bv) {
#pragma unroll
    for (int n = 0; n < 4; ++n) {
      int row = wcc * 64 + n * 16 + fr;
      int slot = fg ^ ((row >> 1) & 3);
      bv[n] = *(const bf16x8*)(rg + row * 32 + slot * 8);
    }
  };
  auto mfma16 = [&](int mh, const bf16x8* af, const bf16x8* bv) {
    __builtin_amdgcn_s_setprio(1);
#pragma unroll
    for (int m = 0; m < 4; ++m)
#pragma unroll
      for (int n = 0; n < 4; ++n)
        acc[mh * 4 + m][n] = __builtin_amdgcn_mfma_f32_16x16x32_bf16(
            af[m], bv[n], acc[mh * 4 + m][n], 0, 0, 0);
    __builtin_amdgcn_s_setprio(0);
  };

#define BAR() __builtin_amdgcn_s_barrier()
#define WAIT6() asm volatile("s_waitcnt vmcnt(6)" ::: "memory")

  bf16x8 afA[4], afB[4], bvA[4], bvB[4];

  stage(0, 0, 0); stage(0, 1, 0); stage(0, 2, 0); stage(0, 3, 0);
  stage(1, 0, 1); stage(1, 1, 1);
  asm volatile("s_waitcnt vmcnt(8)" ::: "memory");
  BAR();
  readA(RA(0, 0), 0, afA); readB(RB(0, 0), bvA);

  for (int t = 0; t < NIT; ++t) {
    int k1 = 2 * t + 1, k2 = 2 * t + 2, k3 = 2 * t + 3;
    if (k2 >= NKT) k2 -= NKT;
    if (k3 >= NKT) k3 -= NKT;
    // p1
    readA(RA(0, 0), 1, afB);
    stage(1, 2, k1);
    BAR(); mfma16(0, afA, bvA); BAR();
    // p2
    WAIT6();
    readA(RA(0, 1), 0, afA); readB(RB(0, 1), bvB);
    stage(1, 3, k1);
    BAR(); mfma16(1, afB, bvA); BAR();
    // p3
    readA(RA(0, 1), 1, afB);
    stage(0, 0, k2);
    BAR(); mfma16(0, afA, bvB); BAR();
    // p4
    WAIT6();
    readA(RA(1, 0), 0, afA); readB(RB(1, 0), bvA);
    stage(0, 1, k2);
    BAR(); mfma16(1, afB, bvB); BAR();
    // p5
    readA(RA(1, 0), 1, afB);
    stage(0, 2, k2);
    BAR(); mfma16(0, afA, bvA); BAR();
    // p6
    WAIT6();
    readA(RA(1, 1), 0, afA); readB(RB(1, 1), bvB);
    stage(0, 3, k2);
    BAR(); mfma16(1, afB, bvA); BAR();
    // p7
    readA(RA(1, 1), 1, afB);
    stage(1, 0, k3);
    BAR(); mfma16(0, afA, bvB); BAR();
    // p8
    WAIT6();
    readA(RA(0, 0), 0, afA); readB(RB(0, 0), bvA);
    stage(1, 1, k3);
    BAR(); mfma16(1, afB, bvB); BAR();
  }
  asm volatile("s_waitcnt vmcnt(0)" ::: "memory");

  float t2v[2][4], vw[4];
#pragma unroll
  for (int n = 0; n < 4; ++n) {
    long col = rowB0 + wcc * 64 + n * 16 + fr;
    vw[n] = Vw[col];
#pragma unroll
    for (int h = 0; h < 2; ++h) {
      long b = (rowA0 >> 6) + wr * 2 + h;
      t2v[h][n] = t2[b * HH + col];
    }
  }
#pragma unroll
  for (int i = 0; i < 8; ++i) {
    int hsel = i >> 2;
    float part[4] = {0.f, 0.f, 0.f, 0.f};
#pragma unroll
    for (int n = 0; n < 4; ++n) {
#pragma unroll
      for (int r = 0; r < 4; ++r) {
        float tval = acc[i][n][r] + t2v[hsel][n];
        float th = 1.f - 2.f / (__expf(2.f * tval) + 1.f);
        part[r] += th * vw[n];
      }
    }
#pragma unroll
    for (int r = 0; r < 4; ++r) {
      float p = part[r];
      p += __shfl_xor(p, 1);
      p += __shfl_xor(p, 2);
      p += __shfl_xor(p, 4);
      p += __shfl_xor(p, 8);
      if (fr == 0)
        atomicAdd(&e[rowA0 + wr * 128 + i * 16 + fg * 4 + r], p);
    }
  }
#undef BAR
#undef WAIT6
}

// ---------------- fused softmax (S=64) + context -> bf16 ----------------
__global__ void softmax_ctx(const float* __restrict__ e,
                            const unsigned short* __restrict__ encb,
                            unsigned short* __restrict__ ctb) {
  __shared__ float als[2][64];
  const int tid = threadIdx.x;
  const int bpair = blockIdx.x;
  if (tid < 128) {
    int b = bpair * 2 + (tid >> 6), s = tid & 63;
    float v = e[b * 64 + s];
    float mx = v;
#pragma unroll
    for (int o = 32; o; o >>= 1) mx = fmaxf(mx, __shfl_xor(mx, o));
    float ex = __expf(v - mx);
    float sm = ex;
#pragma unroll
    for (int o = 32; o; o >>= 1) sm += __shfl_xor(sm, o);
    als[tid >> 6][s] = ex / sm;
  }
  __syncthreads();
  int bi = tid >> 7, hg = tid & 127;
  int b = bpair * 2 + bi;
  const unsigned short* er = encb + (long)b * (SS * HH) + hg * 8;
  float s[8] = {0.f, 0.f, 0.f, 0.f, 0.f, 0.f, 0.f, 0.f};
  for (int i = 0; i < 64; ++i) {
    float av = als[bi][i];
    bf16x8 v = *(const bf16x8*)(er + (long)i * HH);
#pragma unroll
    for (int j = 0; j < 8; ++j) s[j] += av * bf2f((unsigned short)v[j]);
  }
  unsigned short* dst = ctb + (long)b * HH + hg * 8;
#pragma unroll
  for (int j = 0; j < 8; ++j) dst[j] = f2bf(s[j]);
}

// ---------------- LSTM cell elementwise (sums two split-K partials) ----------------
__global__ void lstm_cell(const float* __restrict__ g0, const float* __restrict__ g1,
                          const float* __restrict__ bih, const float* __restrict__ bhh,
                          const float* __restrict__ cin,
                          float* __restrict__ hout, float* __restrict__ cout,
                          unsigned short* __restrict__ hb) {
  int idx = blockIdx.x * 256 + threadIdx.x;  // 512*1024
  int b = idx >> 10, h = idx & 1023;
  const float* gr0 = g0 + (long)b * 4096;
  const float* gr1 = g1 + (long)b * 4096;
  float gi = gr0[h] + gr1[h] + bih[h] + bhh[h];
  float gf = gr0[1024 + h] + gr1[1024 + h] + bih[1024 + h] + bhh[1024 + h];
  float gg = gr0[2048 + h] + gr1[2048 + h] + bih[2048 + h] + bhh[2048 + h];
  float go = gr0[3072 + h] + gr1[3072 + h] + bih[3072 + h] + bhh[3072 + h];
  float si = 1.f / (1.f + __expf(-gi));
  float sf = 1.f / (1.f + __expf(-gf));
  float so = 1.f / (1.f + __expf(-go));
  float tg = 1.f - 2.f / (__expf(2.f * gg) + 1.f);
  float c2 = sf * cin[idx] + si * tg;
  float tc = 1.f - 2.f / (__expf(2.f * c2) + 1.f);
  float h2 = so * tc;
  cout[idx] = c2;
  hout[idx] = h2;
  hb[idx] = f2bf(h2);
}

extern "C" void kernel_launch(void* const* d_in, const int* in_sizes, int n_in,
                              void* d_out, int out_size, void* d_ws, size_t ws_size,
                              hipStream_t stream) {
  const int* ids = (const int*)d_in[0];
  const float* hidden = (const float*)d_in[1];
  const float* cell = (const float*)d_in[2];
  const float* enc = (const float*)d_in[3];
  const float* emb = (const float*)d_in[4];
  const float* U = (const float*)d_in[5];
  const float* W = (const float*)d_in[6];
  const float* Vw = (const float*)d_in[7];
  const float* Wih0 = (const float*)d_in[8];
  const float* Whh0 = (const float*)d_in[9];
  const float* bih0 = (const float*)d_in[10];
  const float* bhh0 = (const float*)d_in[11];
  const float* Wih1 = (const float*)d_in[12];
  const float* Whh1 = (const float*)d_in[13];
  const float* bih1 = (const float*)d_in[14];
  const float* bhh1 = (const float*)d_in[15];
  const float* out_w = (const float*)d_in[16];
  const float* out_b = (const float*)d_in[17];
  float* out = (float*)d_out;
  char* ws = (char*)d_ws;
  (void)in_sizes; (void)n_in; (void)out_size; (void)ws_size;

  unsigned short* enc_b  = (unsigned short*)(ws + OFF_ENC);
  unsigned short* Wih0b  = (unsigned short*)(ws + OFF_WIH0);
  unsigned short* Whh0b  = (unsigned short*)(ws + OFF_WHH0);
  unsigned short* Wih1b  = (unsigned short*)(ws + OFF_WIH1);
  unsigned short* Whh1b  = (unsigned short*)(ws + OFF_WHH1);
  unsigned short* outwb  = (unsigned short*)(ws + OFF_OUTW);
  unsigned short* hid0b  = (unsigned short*)(ws + OFF_HID0);
  unsigned short* hlastb = (unsigned short*)(ws + OFF_HLAST);
  unsigned short* Utb    = (unsigned short*)(ws + OFF_UT);
  unsigned short* Wtb    = (unsigned short*)(ws + OFF_WT);
  float*          t2     = (float*)(ws + OFF_T2);
  float*          e      = (float*)(ws + OFF_E);
  unsigned short* embb   = (unsigned short*)(ws + OFF_EMB);
  unsigned short* ctb    = (unsigned short*)(ws + OFF_CT);
  float*          g      = (float*)(ws + OFF_G);
  float*          gB     = (float*)(ws + OFF_ENC);  // gate partial-1: aliases enc_b (dead after softmax_ctx)
  unsigned short* h0b    = (unsigned short*)(ws + OFF_H0B);
  unsigned short* h1b    = (unsigned short*)(ws + OFF_H1B);

  float* out_logits = out;
  float* h_new = out + BB * VV;
  float* c_new = h_new + 2 * BB * HH;

  // ---- prep: conversions ----
  cvt_fast<<<6416, 256, 0, stream>>>(enc, Wih0, Whh0, Wih1, Whh1, out_w, hidden, ws);
  transpose_cvt2<<<dim3(32, 32, 2), 256, 0, stream>>>(U, W, ws);
  build_xemb<<<128, 256, 0, stream>>>(ids, emb, embb);
  hipMemsetAsync(e, 0, (size_t)BB * SS * 4, stream);

  // ---- t2 = hidden[1] @ W ----
  gemm_seg<<<dim3(4, 16, 1), 256, 0, stream>>>(hlastb, 1024, nullptr, 0, nullptr,
                                               Wtb, 1024, nullptr, t2, t2, HH, 1024, 1024);

  // ---- scores e (256^2 8-phase fused GEMM) ----
  (void)hipFuncSetAttribute(reinterpret_cast<const void*>(gemm_score256),
                            hipFuncAttributeMaxDynamicSharedMemorySize, 131072);
  gemm_score256<<<dim3(4, 128), 512, 131072, stream>>>(enc_b, Utb, t2, Vw, e);

  // ---- fused softmax + context ----
  softmax_ctx<<<256, 256, 0, stream>>>(e, enc_b, ctb);

  // ---- LSTM layer 0: g = [emb | ct | hid0] @ [Wih0 | Whh0]^T, split-K 1152/1152 ----
  gemm_seg<<<dim3(4, 64, 2), 256, 0, stream>>>(embb, 256, ctb, 1024, hid0b,
                                               Wih0b, 1280, Whh0b, g, gB, 4 * HH, 2304, 1152);
  lstm_cell<<<BB * HH / 256, 256, 0, stream>>>(g, gB, bih0, bhh0, cell, h_new, c_new, h0b);

  // ---- LSTM layer 1: g = [h0 | hid1] @ [Wih1 | Whh1]^T, split-K 1024/1024 ----
  gemm_seg<<<dim3(4, 64, 2), 256, 0, stream>>>(h0b, 1024, hlastb, 1024, nullptr,
                                               Wih1b, 1024, Whh1b, g, gB, 4 * HH, 2048, 1024);
  lstm_cell<<<BB * HH / 256, 256, 0, stream>>>(g, gB, bih1, bhh1, cell + BB * HH,
                                               h_new + BB * HH, c_new + BB * HH, h1b);

  // ---- output projection (split-K + bias init) ----
  init_out_bias<<<BB * VV / 256, 256, 0, stream>>>(out_b, out_logits);
  gemm_outproj<<<dim3(4, 8), 256, 0, stream>>>(h1b, outwb, out_logits);
}

// Round 6
// 225.958 us; speedup vs baseline: 1.7332x; 1.0030x over previous
//
#include <hip/hip_runtime.h>
#include <stdint.h>

// dims
#define BB 512
#define SS 64
#define HH 1024
#define EE 256
#define VV 128

typedef __attribute__((ext_vector_type(8))) short bf16x8;
typedef __attribute__((ext_vector_type(4))) float f32x4;
typedef __attribute__((ext_vector_type(8))) unsigned short u16x8;
typedef __attribute__((ext_vector_type(4))) unsigned short u16x4;

// ---- workspace layout (bytes, all 256-aligned) ----
constexpr size_t OFF_ENC   = 0;                           // 32768x1024 bf16 = 64MB (reused as gate partial-1 after softmax_ctx)
constexpr size_t OFF_WIH0  = OFF_ENC   + 67108864UL;      // 4096x1280 bf16
constexpr size_t OFF_WHH0  = OFF_WIH0  + 10485760UL;      // 4096x1024 bf16
constexpr size_t OFF_WIH1  = OFF_WHH0  + 8388608UL;       // 4096x1024 bf16
constexpr size_t OFF_WHH1  = OFF_WIH1  + 8388608UL;       // 4096x1024 bf16
constexpr size_t OFF_OUTW  = OFF_WHH1  + 8388608UL;       // 128x1024 bf16
constexpr size_t OFF_HID0  = OFF_OUTW  + 262144UL;        // 512x1024 bf16 (input hidden[0])
constexpr size_t OFF_HLAST = OFF_HID0  + 1048576UL;       // 512x1024 bf16 (input hidden[1])
constexpr size_t OFF_UT    = OFF_HLAST + 1048576UL;       // 1024x1024 bf16 (U^T)
constexpr size_t OFF_WT    = OFF_UT    + 2097152UL;       // 1024x1024 bf16 (W^T)
constexpr size_t OFF_T2    = OFF_WT    + 2097152UL;       // 512x1024 f32
constexpr size_t OFF_E     = OFF_T2    + 2097152UL;       // 512x64 f32
constexpr size_t OFF_EMB   = OFF_E     + 131072UL;        // 512x256 bf16
constexpr size_t OFF_CT    = OFF_EMB   + 262144UL;        // 512x1024 bf16
constexpr size_t OFF_G     = OFF_CT    + 1048576UL;       // 512x4096 f32 (gate partial-0)
constexpr size_t OFF_H0B   = OFF_G     + 8388608UL;       // 512x1024 bf16 (lstm0 out)
constexpr size_t OFF_H1B   = OFF_H0B   + 1048576UL;       // 512x1024 bf16 (lstm1 out)

__device__ __forceinline__ unsigned short f2bf(float f) {
  unsigned int u = __float_as_uint(f);
  unsigned int r = (u + 0x7FFFu + ((u >> 16) & 1u)) >> 16;
  return (unsigned short)r;
}
__device__ __forceinline__ float bf2f(unsigned short h) {
  return __uint_as_float(((unsigned int)h) << 16);
}

__device__ __forceinline__ void gload_lds16(const void* g, void* l) {
  __builtin_amdgcn_global_load_lds(
      (const __attribute__((address_space(1))) unsigned int*)g,
      (__attribute__((address_space(3))) unsigned int*)l, 16, 0, 0);
}

// ---------------- f32->bf16 conversion, coalesced, block-uniform segments ----------------
// Work quantum per block: 1024 "units" (unit = 8 floats) = 2048 float4s.
// Lane-contiguous: lane i handles float4 index base+i (+j*256), so each load
// instruction covers 1 KB contiguous (m13 copy pattern). 8 loads + 8 stores,
// one basic block.
constexpr long CU0 = 4194304;            // enc
constexpr long CU1 = CU0 + 655360;       // wih0
constexpr long CU2 = CU1 + 524288;       // whh0
constexpr long CU3 = CU2 + 524288;       // wih1
constexpr long CU4 = CU3 + 524288;       // whh1
constexpr long CU5 = CU4 + 16384;        // outw
constexpr long CU6 = CU5 + 65536;        // hid0
constexpr long CU7 = CU6 + 65536;        // hlast (total 6569984 units = 6416 blocks)

__global__ __launch_bounds__(256) void cvt_fast(
    const float* __restrict__ enc, const float* __restrict__ Wih0,
    const float* __restrict__ Whh0, const float* __restrict__ Wih1,
    const float* __restrict__ Whh1, const float* __restrict__ outw,
    const float* __restrict__ hid, char* __restrict__ ws) {
  const long ub = (long)blockIdx.x << 10;   // unit index of block start
  const float* __restrict__ src;
  char* dstb;
  long s0;
  if (ub < CU0)      { src = enc;          dstb = ws + OFF_ENC;   s0 = 0; }
  else if (ub < CU1) { src = Wih0;         dstb = ws + OFF_WIH0;  s0 = CU0; }
  else if (ub < CU2) { src = Whh0;         dstb = ws + OFF_WHH0;  s0 = CU1; }
  else if (ub < CU3) { src = Wih1;         dstb = ws + OFF_WIH1;  s0 = CU2; }
  else if (ub < CU4) { src = Whh1;         dstb = ws + OFF_WHH1;  s0 = CU3; }
  else if (ub < CU5) { src = outw;         dstb = ws + OFF_OUTW;  s0 = CU4; }
  else if (ub < CU6) { src = hid;          dstb = ws + OFF_HID0;  s0 = CU5; }
  else               { src = hid + 524288; dstb = ws + OFF_HLAST; s0 = CU6; }
  const long f4 = (ub - s0) * 2 + threadIdx.x;  // float4 index, lane-contiguous
  const f32x4* __restrict__ sp = (const f32x4*)src;
  u16x4* __restrict__ dp = (u16x4*)dstb;
  // 8 independent coalesced loads, one basic block
  f32x4 v0 = sp[f4 +    0];
  f32x4 v1 = sp[f4 +  256];
  f32x4 v2 = sp[f4 +  512];
  f32x4 v3 = sp[f4 +  768];
  f32x4 v4 = sp[f4 + 1024];
  f32x4 v5 = sp[f4 + 1280];
  f32x4 v6 = sp[f4 + 1536];
  f32x4 v7 = sp[f4 + 1792];
  u16x4 o0, o1, o2, o3, o4, o5, o6, o7;
#define CVT4(o, v) o[0] = f2bf(v[0]); o[1] = f2bf(v[1]); o[2] = f2bf(v[2]); o[3] = f2bf(v[3]);
  CVT4(o0, v0) CVT4(o1, v1) CVT4(o2, v2) CVT4(o3, v3)
  CVT4(o4, v4) CVT4(o5, v5) CVT4(o6, v6) CVT4(o7, v7)
#undef CVT4
  dp[f4 +    0] = o0;
  dp[f4 +  256] = o1;
  dp[f4 +  512] = o2;
  dp[f4 +  768] = o3;
  dp[f4 + 1024] = o4;
  dp[f4 + 1280] = o5;
  dp[f4 + 1536] = o6;
  dp[f4 + 1792] = o7;
}

// ---------------- transpose-convert U and W (z selects) ----------------
__global__ void transpose_cvt2(const float* __restrict__ U, const float* __restrict__ W,
                               char* __restrict__ ws) {
  __shared__ float tile[32][33];
  const float* in = blockIdx.z ? W : U;
  unsigned short* out = (unsigned short*)(ws + (blockIdx.z ? OFF_WT : OFF_UT));
  int bc = blockIdx.x * 32, br = blockIdx.y * 32;
  int tx = threadIdx.x & 31, ty = threadIdx.x >> 5;
#pragma unroll
  for (int i = 0; i < 32; i += 8)
    tile[ty + i][tx] = in[(long)(br + ty + i) * HH + bc + tx];
  __syncthreads();
#pragma unroll
  for (int i = 0; i < 32; i += 8)
    out[(long)(bc + ty + i) * HH + br + tx] = f2bf(tile[tx][ty + i]);
}

// ---------------- embedded token gather -> bf16 ----------------
__global__ void build_xemb(const int* __restrict__ ids, const float* __restrict__ emb,
                           unsigned short* __restrict__ embb) {
  int t = blockIdx.x * 256 + threadIdx.x;  // 32768 = 512 * 64 float4s
  int b = t >> 6, c4 = t & 63;
  float4 v = ((const float4*)(emb + (long)ids[b] * 256))[c4];
  ushort4 o;
  o.x = f2bf(v.x); o.y = f2bf(v.y); o.z = f2bf(v.z); o.w = f2bf(v.w);
  ((ushort4*)embb)[t] = o;
}

// ---------------- segmented bf16 GEMM with split-K: C(z) = A * Bt^T over K-half z ----------------
// BM=128, BN=64, 256 threads (4 waves 2x2). A up to 3 K-segments, B up to 2.
__global__ __launch_bounds__(256) void gemm_seg(
    const unsigned short* __restrict__ A0, int KA0,
    const unsigned short* __restrict__ A1, int KA1,
    const unsigned short* __restrict__ A2,
    const unsigned short* __restrict__ B0, int KB0,
    const unsigned short* __restrict__ B1,
    float* __restrict__ C0p, float* __restrict__ C1p, int N, int Ktot, int Khalf) {
  __shared__ alignas(128) unsigned short lA[128 * 64];
  __shared__ alignas(128) unsigned short lB[64 * 64];
  const int tid = threadIdx.x;
  const int lane = tid & 63, wid = tid >> 6;
  const int wr = wid >> 1, wc = wid & 1;
  const int fr = lane & 15, fg = lane >> 4;
  f32x4 acc[4][2] = {};
  const long rowA0 = (long)blockIdx.x * 128;
  const long rowB0 = (long)blockIdx.y * 64;
  const int ktb = blockIdx.z * Khalf;
  int kte = ktb + Khalf; if (kte > Ktot) kte = Ktot;
  float* C = blockIdx.z ? C1p : C0p;
  for (int kt = ktb; kt < kte; kt += 64) {
    const unsigned short* Ap; int ka, lda;
    if (kt < KA0)            { Ap = A0; ka = kt;             lda = KA0; }
    else if (kt < KA0 + KA1) { Ap = A1; ka = kt - KA0;       lda = KA1; }
    else                     { Ap = A2; ka = kt - KA0 - KA1; lda = 1024; }
    const unsigned short* Bp; int kb, ldb;
    if (kt < KB0) { Bp = B0; kb = kt;       ldb = KB0; }
    else          { Bp = B1; kb = kt - KB0; ldb = 1024; }
#pragma unroll
    for (int j = 0; j < 4; ++j) {
      int c = j * 256 + tid;
      int r = c >> 3, cc = c & 7;
      int sc = cc ^ ((r >> 1) & 7);
      gload_lds16(Ap + (rowA0 + r) * (long)lda + ka + sc * 8, &lA[c * 8]);
    }
#pragma unroll
    for (int j = 0; j < 2; ++j) {
      int c = j * 256 + tid;
      int r = c >> 3, cc = c & 7;
      int sc = cc ^ ((r >> 1) & 7);
      gload_lds16(Bp + (rowB0 + r) * (long)ldb + kb + sc * 8, &lB[c * 8]);
    }
    __syncthreads();
#pragma unroll
    for (int kk = 0; kk < 64; kk += 32) {
      bf16x8 af[4], bfv[2];
#pragma unroll
      for (int m = 0; m < 4; ++m) {
        int row = wr * 64 + m * 16 + fr;
        int ch = ((kk >> 3) + fg) ^ ((row >> 1) & 7);
        af[m] = *(const bf16x8*)&lA[row * 64 + ch * 8];
      }
#pragma unroll
      for (int n = 0; n < 2; ++n) {
        int row = wc * 32 + n * 16 + fr;
        int ch = ((kk >> 3) + fg) ^ ((row >> 1) & 7);
        bfv[n] = *(const bf16x8*)&lB[row * 64 + ch * 8];
      }
#pragma unroll
      for (int m = 0; m < 4; ++m)
#pragma unroll
        for (int n = 0; n < 2; ++n)
          acc[m][n] = __builtin_amdgcn_mfma_f32_16x16x32_bf16(af[m], bfv[n],
                                                              acc[m][n], 0, 0, 0);
    }
    __syncthreads();
  }
#pragma unroll
  for (int m = 0; m < 4; ++m)
#pragma unroll
    for (int n = 0; n < 2; ++n)
#pragma unroll
      for (int r = 0; r < 4; ++r) {
        long grow = rowA0 + wr * 64 + m * 16 + fg * 4 + r;
        long gcol = rowB0 + wc * 32 + n * 16 + fr;
        C[grow * N + gcol] = acc[m][n][r];
      }
}

// ---------------- out projection, split-K, atomic accumulate ----------------
__global__ __launch_bounds__(256) void gemm_outproj(
    const unsigned short* __restrict__ A, const unsigned short* __restrict__ Bt,
    float* __restrict__ C) {
  __shared__ alignas(128) unsigned short lA[128 * 64];
  __shared__ alignas(128) unsigned short lB[128 * 64];
  const int tid = threadIdx.x;
  const int lane = tid & 63, wid = tid >> 6;
  const int wr = wid >> 1, wc = wid & 1;
  const int fr = lane & 15, fg = lane >> 4;
  f32x4 acc[4][4] = {};
  const long rowA0 = (long)blockIdx.x * 128;
  const int k0 = blockIdx.y * 128;
  for (int kt = k0; kt < k0 + 128; kt += 64) {
#pragma unroll
    for (int j = 0; j < 4; ++j) {
      int c = j * 256 + tid;
      int r = c >> 3, cc = c & 7;
      gload_lds16(A + (rowA0 + r) * 1024 + kt + cc * 8, &lA[c * 8]);
    }
#pragma unroll
    for (int j = 0; j < 4; ++j) {
      int c = j * 256 + tid;
      int r = c >> 3, cc = c & 7;
      gload_lds16(Bt + (long)r * 1024 + kt + cc * 8, &lB[c * 8]);
    }
    __syncthreads();
#pragma unroll
    for (int kk = 0; kk < 64; kk += 32) {
      bf16x8 af[4], bfv[4];
#pragma unroll
      for (int m = 0; m < 4; ++m)
        af[m] = *(const bf16x8*)&lA[(wr * 64 + m * 16 + fr) * 64 + kk + fg * 8];
#pragma unroll
      for (int n = 0; n < 4; ++n)
        bfv[n] = *(const bf16x8*)&lB[(wc * 64 + n * 16 + fr) * 64 + kk + fg * 8];
#pragma unroll
      for (int m = 0; m < 4; ++m)
#pragma unroll
        for (int n = 0; n < 4; ++n)
          acc[m][n] = __builtin_amdgcn_mfma_f32_16x16x32_bf16(af[m], bfv[n],
                                                              acc[m][n], 0, 0, 0);
    }
    __syncthreads();
  }
#pragma unroll
  for (int m = 0; m < 4; ++m)
#pragma unroll
    for (int n = 0; n < 4; ++n)
#pragma unroll
      for (int r = 0; r < 4; ++r) {
        long grow = rowA0 + wr * 64 + m * 16 + fg * 4 + r;
        long gcol = wc * 64 + n * 16 + fr;
        atomicAdd(&C[grow * 128 + gcol], acc[m][n][r]);
      }
}

__global__ void init_out_bias(const float* __restrict__ ob, float* __restrict__ out) {
  int i = blockIdx.x * 256 + threadIdx.x;
  out[i] = ob[i & 127];
}

// ---------------- 256x256 8-phase score GEMM with reg-prefetch + XCD swizzle ----------------
__global__ __launch_bounds__(512, 2) void gemm_score256(
    const unsigned short* __restrict__ A, const unsigned short* __restrict__ Bt,
    const float* __restrict__ t2, const float* __restrict__ Vw,
    float* __restrict__ e) {
  extern __shared__ unsigned short smem[];  // [2][4][8192]
  const int K = HH;
  const int tid = threadIdx.x;
  const int lane = tid & 63, wid = tid >> 6;
  const int wr = wid >> 2;       // M half (128 rows)
  const int wcc = wid & 3;       // N quarter (64 cols)
  const int fr = lane & 15, fg = lane >> 4;
  int flat = blockIdx.y * 4 + blockIdx.x;
  int swz = (flat & 7) * 64 + (flat >> 3);
  const long rowA0 = (long)(swz >> 2) * 256;
  const long rowB0 = (long)(swz & 3) * 256;
  const int NKT = 16, NIT = 8;

  f32x4 acc[8][4] = {};

  auto RA = [&](int buf, int kh) { return (const unsigned short*)(smem + (buf * 4 + kh * 2) * 8192); };
  auto RB = [&](int buf, int kh) { return (const unsigned short*)(smem + (buf * 4 + kh * 2 + 1) * 8192); };

  auto stage = [&](int buf, int reg, int ktile) {
    const unsigned short* base = (reg & 1) ? Bt : A;
    long r0 = (reg & 1) ? rowB0 : rowA0;
    int kb = ktile * 64 + (reg >> 1) * 32;
    unsigned short* dst = smem + (buf * 4 + reg) * 8192;
#pragma unroll
    for (int j = 0; j < 2; ++j) {
      int c = j * 512 + tid;
      int row = c >> 2;
      int fgl = (c & 3) ^ ((row >> 1) & 3);
      gload_lds16(base + (r0 + row) * (long)K + kb + fgl * 8, dst + c * 8);
    }
  };
  auto readA = [&](const unsigned short* rg, int mh, bf16x8* af) {
#pragma unroll
    for (int m = 0; m < 4; ++m) {
      int row = wr * 128 + mh * 64 + m * 16 + fr;
      int slot = fg ^ ((row >> 1) & 3);
      af[m] = *(const bf16x8*)(rg + row * 32 + slot * 8);
    }
  };
  auto readB = [&](const unsigned short* rg, bf16x8* bv) {
#pragma unroll
    for (int n = 0; n < 4; ++n) {
      int row = wcc * 64 + n * 16 + fr;
      int slot = fg ^ ((row >> 1) & 3);
      bv[n] = *(const bf16x8*)(rg + row * 32 + slot * 8);
    }
  };
  auto mfma16 = [&](int mh, const bf16x8* af, const bf16x8* bv) {
    __builtin_amdgcn_s_setprio(1);
#pragma unroll
    for (int m = 0; m < 4; ++m)
#pragma unroll
      for (int n = 0; n < 4; ++n)
        acc[mh * 4 + m][n] = __builtin_amdgcn_mfma_f32_16x16x32_bf16(
            af[m], bv[n], acc[mh * 4 + m][n], 0, 0, 0);
    __builtin_amdgcn_s_setprio(0);
  };

#define BAR() __builtin_amdgcn_s_barrier()
#define WAIT6() asm volatile("s_waitcnt vmcnt(6)" ::: "memory")

  bf16x8 afA[4], afB[4], bvA[4], bvB[4];

  stage(0, 0, 0); stage(0, 1, 0); stage(0, 2, 0); stage(0, 3, 0);
  stage(1, 0, 1); stage(1, 1, 1);
  asm volatile("s_waitcnt vmcnt(8)" ::: "memory");
  BAR();
  readA(RA(0, 0), 0, afA); readB(RB(0, 0), bvA);

  for (int t = 0; t < NIT; ++t) {
    int k1 = 2 * t + 1, k2 = 2 * t + 2, k3 = 2 * t + 3;
    if (k2 >= NKT) k2 -= NKT;
    if (k3 >= NKT) k3 -= NKT;
    // p1
    readA(RA(0, 0), 1, afB);
    stage(1, 2, k1);
    BAR(); mfma16(0, afA, bvA); BAR();
    // p2
    WAIT6();
    readA(RA(0, 1), 0, afA); readB(RB(0, 1), bvB);
    stage(1, 3, k1);
    BAR(); mfma16(1, afB, bvA); BAR();
    // p3
    readA(RA(0, 1), 1, afB);
    stage(0, 0, k2);
    BAR(); mfma16(0, afA, bvB); BAR();
    // p4
    WAIT6();
    readA(RA(1, 0), 0, afA); readB(RB(1, 0), bvA);
    stage(0, 1, k2);
    BAR(); mfma16(1, afB, bvB); BAR();
    // p5
    readA(RA(1, 0), 1, afB);
    stage(0, 2, k2);
    BAR(); mfma16(0, afA, bvA); BAR();
    // p6
    WAIT6();
    readA(RA(1, 1), 0, afA); readB(RB(1, 1), bvB);
    stage(0, 3, k2);
    BAR(); mfma16(1, afB, bvA); BAR();
    // p7
    readA(RA(1, 1), 1, afB);
    stage(1, 0, k3);
    BAR(); mfma16(0, afA, bvB); BAR();
    // p8
    WAIT6();
    readA(RA(0, 0), 0, afA); readB(RB(0, 0), bvA);
    stage(1, 1, k3);
    BAR(); mfma16(1, afB, bvB); BAR();
  }
  asm volatile("s_waitcnt vmcnt(0)" ::: "memory");

  float t2v[2][4], vw[4];
#pragma unroll
  for (int n = 0; n < 4; ++n) {
    long col = rowB0 + wcc * 64 + n * 16 + fr;
    vw[n] = Vw[col];
#pragma unroll
    for (int h = 0; h < 2; ++h) {
      long b = (rowA0 >> 6) + wr * 2 + h;
      t2v[h][n] = t2[b * HH + col];
    }
  }
#pragma unroll
  for (int i = 0; i < 8; ++i) {
    int hsel = i >> 2;
    float part[4] = {0.f, 0.f, 0.f, 0.f};
#pragma unroll
    for (int n = 0; n < 4; ++n) {
#pragma unroll
      for (int r = 0; r < 4; ++r) {
        float tval = acc[i][n][r] + t2v[hsel][n];
        float th = 1.f - 2.f / (__expf(2.f * tval) + 1.f);
        part[r] += th * vw[n];
      }
    }
#pragma unroll
    for (int r = 0; r < 4; ++r) {
      float p = part[r];
      p += __shfl_xor(p, 1);
      p += __shfl_xor(p, 2);
      p += __shfl_xor(p, 4);
      p += __shfl_xor(p, 8);
      if (fr == 0)
        atomicAdd(&e[rowA0 + wr * 128 + i * 16 + fg * 4 + r], p);
    }
  }
#undef BAR
#undef WAIT6
}

// ---------------- fused softmax (S=64) + context -> bf16 ----------------
__global__ void softmax_ctx(const float* __restrict__ e,
                            const unsigned short* __restrict__ encb,
                            unsigned short* __restrict__ ctb) {
  __shared__ float als[2][64];
  const int tid = threadIdx.x;
  const int bpair = blockIdx.x;
  if (tid < 128) {
    int b = bpair * 2 + (tid >> 6), s = tid & 63;
    float v = e[b * 64 + s];
    float mx = v;
#pragma unroll
    for (int o = 32; o; o >>= 1) mx = fmaxf(mx, __shfl_xor(mx, o));
    float ex = __expf(v - mx);
    float sm = ex;
#pragma unroll
    for (int o = 32; o; o >>= 1) sm += __shfl_xor(sm, o);
    als[tid >> 6][s] = ex / sm;
  }
  __syncthreads();
  int bi = tid >> 7, hg = tid & 127;
  int b = bpair * 2 + bi;
  const unsigned short* er = encb + (long)b * (SS * HH) + hg * 8;
  float s[8] = {0.f, 0.f, 0.f, 0.f, 0.f, 0.f, 0.f, 0.f};
  for (int i = 0; i < 64; ++i) {
    float av = als[bi][i];
    bf16x8 v = *(const bf16x8*)(er + (long)i * HH);
#pragma unroll
    for (int j = 0; j < 8; ++j) s[j] += av * bf2f((unsigned short)v[j]);
  }
  unsigned short* dst = ctb + (long)b * HH + hg * 8;
#pragma unroll
  for (int j = 0; j < 8; ++j) dst[j] = f2bf(s[j]);
}

// ---------------- LSTM cell elementwise (sums two split-K partials) ----------------
__global__ void lstm_cell(const float* __restrict__ g0, const float* __restrict__ g1,
                          const float* __restrict__ bih, const float* __restrict__ bhh,
                          const float* __restrict__ cin,
                          float* __restrict__ hout, float* __restrict__ cout,
                          unsigned short* __restrict__ hb) {
  int idx = blockIdx.x * 256 + threadIdx.x;  // 512*1024
  int b = idx >> 10, h = idx & 1023;
  const float* gr0 = g0 + (long)b * 4096;
  const float* gr1 = g1 + (long)b * 4096;
  float gi = gr0[h] + gr1[h] + bih[h] + bhh[h];
  float gf = gr0[1024 + h] + gr1[1024 + h] + bih[1024 + h] + bhh[1024 + h];
  float gg = gr0[2048 + h] + gr1[2048 + h] + bih[2048 + h] + bhh[2048 + h];
  float go = gr0[3072 + h] + gr1[3072 + h] + bih[3072 + h] + bhh[3072 + h];
  float si = 1.f / (1.f + __expf(-gi));
  float sf = 1.f / (1.f + __expf(-gf));
  float so = 1.f / (1.f + __expf(-go));
  float tg = 1.f - 2.f / (__expf(2.f * gg) + 1.f);
  float c2 = sf * cin[idx] + si * tg;
  float tc = 1.f - 2.f / (__expf(2.f * c2) + 1.f);
  float h2 = so * tc;
  cout[idx] = c2;
  hout[idx] = h2;
  hb[idx] = f2bf(h2);
}

extern "C" void kernel_launch(void* const* d_in, const int* in_sizes, int n_in,
                              void* d_out, int out_size, void* d_ws, size_t ws_size,
                              hipStream_t stream) {
  const int* ids = (const int*)d_in[0];
  const float* hidden = (const float*)d_in[1];
  const float* cell = (const float*)d_in[2];
  const float* enc = (const float*)d_in[3];
  const float* emb = (const float*)d_in[4];
  const float* U = (const float*)d_in[5];
  const float* W = (const float*)d_in[6];
  const float* Vw = (const float*)d_in[7];
  const float* Wih0 = (const float*)d_in[8];
  const float* Whh0 = (const float*)d_in[9];
  const float* bih0 = (const float*)d_in[10];
  const float* bhh0 = (const float*)d_in[11];
  const float* Wih1 = (const float*)d_in[12];
  const float* Whh1 = (const float*)d_in[13];
  const float* bih1 = (const float*)d_in[14];
  const float* bhh1 = (const float*)d_in[15];
  const float* out_w = (const float*)d_in[16];
  const float* out_b = (const float*)d_in[17];
  float* out = (float*)d_out;
  char* ws = (char*)d_ws;
  (void)in_sizes; (void)n_in; (void)out_size; (void)ws_size;

  unsigned short* enc_b  = (unsigned short*)(ws + OFF_ENC);
  unsigned short* Wih0b  = (unsigned short*)(ws + OFF_WIH0);
  unsigned short* Whh0b  = (unsigned short*)(ws + OFF_WHH0);
  unsigned short* Wih1b  = (unsigned short*)(ws + OFF_WIH1);
  unsigned short* Whh1b  = (unsigned short*)(ws + OFF_WHH1);
  unsigned short* outwb  = (unsigned short*)(ws + OFF_OUTW);
  unsigned short* hid0b  = (unsigned short*)(ws + OFF_HID0);
  unsigned short* hlastb = (unsigned short*)(ws + OFF_HLAST);
  unsigned short* Utb    = (unsigned short*)(ws + OFF_UT);
  unsigned short* Wtb    = (unsigned short*)(ws + OFF_WT);
  float*          t2     = (float*)(ws + OFF_T2);
  float*          e      = (float*)(ws + OFF_E);
  unsigned short* embb   = (unsigned short*)(ws + OFF_EMB);
  unsigned short* ctb    = (unsigned short*)(ws + OFF_CT);
  float*          g      = (float*)(ws + OFF_G);
  float*          gB     = (float*)(ws + OFF_ENC);  // gate partial-1: aliases enc_b (dead after softmax_ctx)
  unsigned short* h0b    = (unsigned short*)(ws + OFF_H0B);
  unsigned short* h1b    = (unsigned short*)(ws + OFF_H1B);

  float* out_logits = out;
  float* h_new = out + BB * VV;
  float* c_new = h_new + 2 * BB * HH;

  // ---- prep: conversions ----
  cvt_fast<<<6416, 256, 0, stream>>>(enc, Wih0, Whh0, Wih1, Whh1, out_w, hidden, ws);
  transpose_cvt2<<<dim3(32, 32, 2), 256, 0, stream>>>(U, W, ws);
  build_xemb<<<128, 256, 0, stream>>>(ids, emb, embb);
  hipMemsetAsync(e, 0, (size_t)BB * SS * 4, stream);

  // ---- t2 = hidden[1] @ W ----
  gemm_seg<<<dim3(4, 16, 1), 256, 0, stream>>>(hlastb, 1024, nullptr, 0, nullptr,
                                               Wtb, 1024, nullptr, t2, t2, HH, 1024, 1024);

  // ---- scores e (256^2 8-phase fused GEMM) ----
  (void)hipFuncSetAttribute(reinterpret_cast<const void*>(gemm_score256),
                            hipFuncAttributeMaxDynamicSharedMemorySize, 131072);
  gemm_score256<<<dim3(4, 128), 512, 131072, stream>>>(enc_b, Utb, t2, Vw, e);

  // ---- fused softmax + context ----
  softmax_ctx<<<256, 256, 0, stream>>>(e, enc_b, ctb);

  // ---- LSTM layer 0: g = [emb | ct | hid0] @ [Wih0 | Whh0]^T, split-K 1152/1152 ----
  gemm_seg<<<dim3(4, 64, 2), 256, 0, stream>>>(embb, 256, ctb, 1024, hid0b,
                                               Wih0b, 1280, Whh0b, g, gB, 4 * HH, 2304, 1152);
  lstm_cell<<<BB * HH / 256, 256, 0, stream>>>(g, gB, bih0, bhh0, cell, h_new, c_new, h0b);

  // ---- LSTM layer 1: g = [h0 | hid1] @ [Wih1 | Whh1]^T, split-K 1024/1024 ----
  gemm_seg<<<dim3(4, 64, 2), 256, 0, stream>>>(h0b, 1024, hlastb, 1024, nullptr,
                                               Wih1b, 1024, Whh1b, g, gB, 4 * HH, 2048, 1024);
  lstm_cell<<<BB * HH / 256, 256, 0, stream>>>(g, gB, bih1, bhh1, cell + BB * HH,
                                               h_new + BB * HH, c_new + BB * HH, h1b);

  // ---- output projection (split-K + bias init) ----
  init_out_bias<<<BB * VV / 256, 256, 0, stream>>>(out_b, out_logits);
  gemm_outproj<<<dim3(4, 8), 256, 0, stream>>>(h1b, outwb, out_logits);
}